// Round 3
// baseline (553.817 us; speedup 1.0000x reference)
//
#include <hip/hip_runtime.h>
#include <math.h>

#define P_ 32
#define G_ 256
#define NV 6890
#define M_ (2 * NV)          // 13780 joint points per sample
#define QUADS (M_ / 4)       // 3445 vertex-quads; also float4s per SoA plane
#define NPAIR (P_ * G_)      // 8192
#define NB_CC 512            // fallback crosscov blocks
#define SAMPLES (P_ + G_)    // 288
#define NCHUNK 14            // ceil(QUADS / 256)
#define SAMPLE_F4 (3 * QUADS) // 10335 float4 per sample

typedef float v2f __attribute__((ext_vector_type(2)));
__device__ inline v2f v2(float a, float b) { v2f r; r.x = a; r.y = b; return r; }
__device__ inline v2f vsplat(float a) { v2f r; r.x = a; r.y = a; return r; }
__device__ inline v2f vfma(v2f a, v2f b, v2f c) { return __builtin_elementwise_fma(a, b, c); }

// ---------------- workspace layout ----------------
struct WS {
    double stat[SAMPLES][4];       // atomic sums: x, y, z, (sumsq for preds)
    float soa[SAMPLES * 3 * M_];   // 47.6 MB transposed copy
    float mu_p[P_][3];             // fallback-path stats
    float var_p[P_];
    float mu_g[G_][3];
    float At[NPAIR][12];     // A = scale*R (9) then t (3); pair = g*32 + p
    float Kmat[NPAIR][9];    // cross-covariance (pre mean-subtraction)
    float pair_err[NPAIR];   // mean v2v error per pair
};

// ---------------- block reduction (valid on thread 0) ----------------
__device__ inline double block_reduce(double v, double* smem) {
#pragma unroll
    for (int off = 32; off > 0; off >>= 1) v += __shfl_down(v, off, 64);
    int wid  = threadIdx.x >> 6;
    int lane = threadIdx.x & 63;
    __syncthreads();
    if (lane == 0) smem[wid] = v;
    __syncthreads();
    double r = 0.0;
    if (threadIdx.x == 0) {
        int nw = blockDim.x >> 6;
        for (int w = 0; w < nw; ++w) r += smem[w];
    }
    return r;
}

// ---------------- kernel 0: AoS -> SoA repack + fused stats ----
__global__ __launch_bounds__(256) void repack_stats(const float* __restrict__ pred,
                                                    const float* __restrict__ gt,
                                                    WS* __restrict__ ws) {
    int bx = blockIdx.x;
    int s = bx / NCHUNK;
    int chunk = bx - s * NCHUNK;
    bool isP = (s < P_);
    const float4* src4 = (const float4*)(isP ? pred + (size_t)s * (M_ * 3)
                                             : gt + (size_t)(s - P_) * (M_ * 3));
    __shared__ __align__(16) float lds[256 * 12];   // 12 KB chunk staging
    int t = threadIdx.x;
    int f4base = chunk * (256 * 3);
#pragma unroll
    for (int k = 0; k < 3; ++k) {
        int f4 = f4base + k * 256 + t;
        if (f4 < SAMPLE_F4) ((float4*)lds)[k * 256 + t] = src4[f4];
    }
    __syncthreads();
    int q = chunk * 256 + t;
    double sx = 0, sy = 0, sz = 0, sq = 0;
    if (q < QUADS) {
        const float* v = lds + 12 * t;
        float4 X = make_float4(v[0], v[3], v[6], v[9]);
        float4 Y = make_float4(v[1], v[4], v[7], v[10]);
        float4 Z = make_float4(v[2], v[5], v[8], v[11]);
        float4* dst = (float4*)ws->soa;
        dst[(size_t)(s * 3 + 0) * QUADS + q] = X;
        dst[(size_t)(s * 3 + 1) * QUADS + q] = Y;
        dst[(size_t)(s * 3 + 2) * QUADS + q] = Z;
        sx = (double)X.x + (double)X.y + (double)X.z + (double)X.w;
        sy = (double)Y.x + (double)Y.y + (double)Y.z + (double)Y.w;
        sz = (double)Z.x + (double)Z.y + (double)Z.z + (double)Z.w;
        if (isP) {
            sq = (double)X.x * X.x + (double)X.y * X.y + (double)X.z * X.z +
                 (double)X.w * X.w + (double)Y.x * Y.x + (double)Y.y * Y.y +
                 (double)Y.z * Y.z + (double)Y.w * Y.w + (double)Z.x * Z.x +
                 (double)Z.y * Z.y + (double)Z.z * Z.z + (double)Z.w * Z.w;
        }
    }
    __shared__ double smem[4];
    double rx = block_reduce(sx, smem);
    double ry = block_reduce(sy, smem);
    double rz = block_reduce(sz, smem);
    double rq = block_reduce(sq, smem);
    if (t == 0) {
        atomicAdd(&ws->stat[s][0], rx);
        atomicAdd(&ws->stat[s][1], ry);
        atomicAdd(&ws->stat[s][2], rz);
        if (isP) atomicAdd(&ws->stat[s][3], rq);
    }
}

// ---------------- kernel 1: crosscov on SoA, 4p x 4g tiles ----------------
// 512 blocks = ptile(8)*64 + gtile(64); XCD = gtile%8. Traffic per block =
// 8 samples * 165KB; total 676 MB (vs 1.0 GB at 2p). 144 acc floats + 60
// load floats ~= 215 VGPR, no launch_bounds cap -> no spill, 2 waves/SIMD.
#define CC_VERT(i, px, py, pz, gxy, gz)                  \
    a01[i] = vfma(vsplat(px), gxy, a01[i]);              \
    a34[i] = vfma(vsplat(py), gxy, a34[i]);              \
    a67[i] = vfma(vsplat(pz), gxy, a67[i]);              \
    a25[i] = vfma(v2(px, py), vsplat(gz), a25[i]);       \
    a8[i]  = fmaf(pz, gz, a8[i]);

__global__ void crosscov_soa(WS* __restrict__ ws) {
    int bx = blockIdx.x;
    int gbase = (bx & 63) * 4;
    int pbase = (bx >> 6) * 4;   // 8 ptiles
    int t = threadIdx.x;
    const float4* soa4 = (const float4*)ws->soa;

    // wave-uniform plane pointers (SGPR bases); loads index by [q] only
    const float4* ppx[4]; const float4* ppy[4]; const float4* ppz[4];
    const float4* gpx[4]; const float4* gpy[4]; const float4* gpz[4];
#pragma unroll
    for (int j = 0; j < 4; ++j) {
        const float4* b = soa4 + (size_t)(pbase + j) * SAMPLE_F4;
        ppx[j] = b; ppy[j] = b + QUADS; ppz[j] = b + 2 * QUADS;
        const float4* c = soa4 + (size_t)(P_ + gbase + j) * SAMPLE_F4;
        gpx[j] = c; gpy[j] = c + QUADS; gpz[j] = c + 2 * QUADS;
    }

    v2f a01[16], a34[16], a67[16], a25[16];
    float a8[16];
#pragma unroll
    for (int i = 0; i < 16; ++i) {
        a01[i] = vsplat(0.f); a34[i] = vsplat(0.f);
        a67[i] = vsplat(0.f); a25[i] = vsplat(0.f);
        a8[i] = 0.f;
    }

    for (int q = t; q < QUADS; q += 256) {
        float4 PX[4], PY[4], PZ[4];
#pragma unroll
        for (int j = 0; j < 4; ++j) {
            PX[j] = ppx[j][q];
            PY[j] = ppy[j][q];
            PZ[j] = ppz[j][q];
        }
#pragma unroll
        for (int gg = 0; gg < 4; ++gg) {
            float4 GX = gpx[gg][q];
            float4 GY = gpy[gg][q];
            float4 GZ = gpz[gg][q];
            v2f gxy0 = v2(GX.x, GY.x), gxy1 = v2(GX.y, GY.y);
            v2f gxy2 = v2(GX.z, GY.z), gxy3 = v2(GX.w, GY.w);
#pragma unroll
            for (int pp = 0; pp < 4; ++pp) {
                int i = gg * 4 + pp;
                CC_VERT(i, PX[pp].x, PY[pp].x, PZ[pp].x, gxy0, GZ.x)
                CC_VERT(i, PX[pp].y, PY[pp].y, PZ[pp].y, gxy1, GZ.y)
                CC_VERT(i, PX[pp].z, PY[pp].z, PZ[pp].z, gxy2, GZ.z)
                CC_VERT(i, PX[pp].w, PY[pp].w, PZ[pp].w, gxy3, GZ.w)
            }
        }
    }

    float K[16][9];
#pragma unroll
    for (int i = 0; i < 16; ++i) {
        K[i][0] = a01[i].x; K[i][1] = a01[i].y; K[i][2] = a25[i].x;
        K[i][3] = a34[i].x; K[i][4] = a34[i].y; K[i][5] = a25[i].y;
        K[i][6] = a67[i].x; K[i][7] = a67[i].y; K[i][8] = a8[i];
    }
#pragma unroll
    for (int i = 0; i < 16; ++i)
#pragma unroll
        for (int j = 0; j < 9; ++j) {
            float v = K[i][j];
            v += __shfl_xor(v, 1);  v += __shfl_xor(v, 2);
            v += __shfl_xor(v, 4);  v += __shfl_xor(v, 8);
            v += __shfl_xor(v, 16); v += __shfl_xor(v, 32);
            K[i][j] = v;
        }
    __shared__ float part[4][144];
    int lane = t & 63, wave = t >> 6;
    if (lane == 0) {
#pragma unroll
        for (int i = 0; i < 16; ++i)
#pragma unroll
            for (int j = 0; j < 9; ++j) part[wave][i * 9 + j] = K[i][j];
    }
    __syncthreads();
    if (t < 144) {
        float s = part[0][t] + part[1][t] + part[2][t] + part[3][t];
        int idx = t / 9, j = t % 9;
        int gg = idx >> 2, pp = idx & 3;
        ws->Kmat[(gbase + gg) * P_ + (pbase + pp)][j] = s;
    }
}

// ---------------- kernel 2: per-pair SVD -> A = scale*R, t ----------------
__global__ void pair_svd(WS* __restrict__ ws, int use_stat) {
    int pair = blockIdx.x * blockDim.x + threadIdx.x;
    if (pair >= NPAIR) return;
    int p = pair & 31;
    int g = pair >> 5;

    double mp[3], mg[3], varp;
    if (use_stat) {
        const double invM = 1.0 / (double)M_;
        mp[0] = ws->stat[p][0] * invM;
        mp[1] = ws->stat[p][1] * invM;
        mp[2] = ws->stat[p][2] * invM;
        mg[0] = ws->stat[P_ + g][0] * invM;
        mg[1] = ws->stat[P_ + g][1] * invM;
        mg[2] = ws->stat[P_ + g][2] * invM;
        varp = ws->stat[p][3] - (mp[0] * mp[0] + mp[1] * mp[1] + mp[2] * mp[2]) * (double)M_;
    } else {
        mp[0] = ws->mu_p[p][0]; mp[1] = ws->mu_p[p][1]; mp[2] = ws->mu_p[p][2];
        mg[0] = ws->mu_g[g][0]; mg[1] = ws->mu_g[g][1]; mg[2] = ws->mu_g[g][2];
        varp = (double)ws->var_p[p];
    }

    double K[3][3];
#pragma unroll
    for (int a = 0; a < 3; ++a)
#pragma unroll
        for (int b = 0; b < 3; ++b)
            K[a][b] = (double)ws->Kmat[pair][3 * a + b] - (double)M_ * mp[a] * mg[b];

    // S = K^T K (symmetric PSD)
    double S[3][3];
#pragma unroll
    for (int a = 0; a < 3; ++a)
#pragma unroll
        for (int b = 0; b < 3; ++b) {
            double acc = 0.0;
#pragma unroll
            for (int c = 0; c < 3; ++c) acc += K[c][a] * K[c][b];
            S[a][b] = acc;
        }

    // Jacobi eigendecomposition S = V Lambda V^T
    double V[3][3] = { {1, 0, 0}, {0, 1, 0}, {0, 0, 1} };
    double tr = S[0][0] + S[1][1] + S[2][2];
    double tol = 1e-30 * tr * tr + 1e-300;
    const int PP[3] = {0, 0, 1};
    const int QQ[3] = {1, 2, 2};
    for (int sweep = 0; sweep < 30; ++sweep) {
        double off = S[0][1] * S[0][1] + S[0][2] * S[0][2] + S[1][2] * S[1][2];
        if (off <= tol) break;
        for (int r3 = 0; r3 < 3; ++r3) {
            int pq = PP[r3], qq = QQ[r3];
            double apq = S[pq][qq];
            if (apq == 0.0) continue;
            double theta = (S[qq][qq] - S[pq][pq]) / (2.0 * apq);
            double tt = copysign(1.0, theta) / (fabs(theta) + sqrt(theta * theta + 1.0));
            double c = 1.0 / sqrt(tt * tt + 1.0);
            double sj = tt * c;
            for (int r = 0; r < 3; ++r) {
                double srp = S[r][pq], srq = S[r][qq];
                S[r][pq] = c * srp - sj * srq;
                S[r][qq] = sj * srp + c * srq;
            }
            for (int cc = 0; cc < 3; ++cc) {
                double spr = S[pq][cc], sqr = S[qq][cc];
                S[pq][cc] = c * spr - sj * sqr;
                S[qq][cc] = sj * spr + c * sqr;
            }
            for (int r = 0; r < 3; ++r) {
                double vrp = V[r][pq], vrq = V[r][qq];
                V[r][pq] = c * vrp - sj * vrq;
                V[r][qq] = sj * vrp + c * vrq;
            }
        }
    }

    double lam[3] = { S[0][0], S[1][1], S[2][2] };
    int idx[3] = { 0, 1, 2 };
    if (lam[idx[0]] < lam[idx[1]]) { int tt = idx[0]; idx[0] = idx[1]; idx[1] = tt; }
    if (lam[idx[0]] < lam[idx[2]]) { int tt = idx[0]; idx[0] = idx[2]; idx[2] = tt; }
    if (lam[idx[1]] < lam[idx[2]]) { int tt = idx[1]; idx[1] = idx[2]; idx[2] = tt; }
    double Vs[3][3];
    double sv[3];
#pragma unroll
    for (int i = 0; i < 3; ++i) {
        double l = lam[idx[i]];
        sv[i] = sqrt(l > 0.0 ? l : 0.0);
        for (int r = 0; r < 3; ++r) Vs[r][i] = V[r][idx[i]];
    }

    double U[3][3];
#pragma unroll
    for (int i = 0; i < 3; ++i) {
        double kx = K[0][0] * Vs[0][i] + K[0][1] * Vs[1][i] + K[0][2] * Vs[2][i];
        double ky = K[1][0] * Vs[0][i] + K[1][1] * Vs[1][i] + K[1][2] * Vs[2][i];
        double kz = K[2][0] * Vs[0][i] + K[2][1] * Vs[1][i] + K[2][2] * Vs[2][i];
        double inv = (sv[i] > 1e-12 * sv[0] && sv[i] > 0.0) ? 1.0 / sv[i] : 0.0;
        U[0][i] = kx * inv; U[1][i] = ky * inv; U[2][i] = kz * inv;
    }
    if (sv[2] <= 1e-12 * sv[0] || sv[0] == 0.0) {
        U[0][2] = U[1][0] * U[2][1] - U[2][0] * U[1][1];
        U[1][2] = U[2][0] * U[0][1] - U[0][0] * U[2][1];
        U[2][2] = U[0][0] * U[1][1] - U[1][0] * U[0][1];
    }

    double detK = K[0][0] * (K[1][1] * K[2][2] - K[1][2] * K[2][1])
                - K[0][1] * (K[1][0] * K[2][2] - K[1][2] * K[2][0])
                + K[0][2] * (K[1][0] * K[2][1] - K[1][1] * K[2][0]);
    double d = (detK >= 0.0) ? 1.0 : -1.0;
    double scale = (sv[0] + sv[1] + d * sv[2]) / varp;

    float A[9];
#pragma unroll
    for (int a = 0; a < 3; ++a)
#pragma unroll
        for (int b = 0; b < 3; ++b) {
            double r = Vs[a][0] * U[b][0] + Vs[a][1] * U[b][1] + d * Vs[a][2] * U[b][2];
            A[3 * a + b] = (float)(scale * r);
        }
    float tvec[3];
#pragma unroll
    for (int a = 0; a < 3; ++a)
        tvec[a] = (float)(mg[a] - ((double)A[3 * a + 0] * mp[0] + (double)A[3 * a + 1] * mp[1] +
                                   (double)A[3 * a + 2] * mp[2]));

#pragma unroll
    for (int j = 0; j < 9; ++j) ws->At[pair][j] = A[j];
#pragma unroll
    for (int j = 0; j < 3; ++j) ws->At[pair][9 + j] = tvec[j];
}

// ---------------- kernel 3: v2v error on SoA (4p x 4g) ---------
// 512 blocks. At consts (192 floats) are block-uniform -> scalarized into
// SGPRs (as measured at 2p: VGPR=48/SGPR=112); overflow goes to VGPR.
__global__ void pair_error_soa(WS* __restrict__ ws) {
    int bx = blockIdx.x;
    int gbase = (bx & 63) * 4;
    int pbase = (bx >> 6) * 4;
    int t = threadIdx.x;

    v2f a03[16], a14[16], a25v[16], t01[16];
    float a6[16], a7[16], a8v[16], t2[16];
#pragma unroll
    for (int gg = 0; gg < 4; ++gg)
#pragma unroll
        for (int pp = 0; pp < 4; ++pp) {
            int i = gg * 4 + pp;
            const float* At = ws->At[(gbase + gg) * P_ + (pbase + pp)];
            a03[i] = v2(At[0], At[3]);
            a14[i] = v2(At[1], At[4]);
            a25v[i] = v2(At[2], At[5]);
            t01[i] = v2(At[9], At[10]);
            a6[i] = At[6]; a7[i] = At[7]; a8v[i] = At[8]; t2[i] = At[11];
        }

    const float4* soa4 = (const float4*)ws->soa;
    const float4* ppx[4]; const float4* ppy[4]; const float4* ppz[4];
    const float4* gpx[4]; const float4* gpy[4]; const float4* gpz[4];
#pragma unroll
    for (int j = 0; j < 4; ++j) {
        const float4* b = soa4 + (size_t)(pbase + j) * SAMPLE_F4;
        ppx[j] = b; ppy[j] = b + QUADS; ppz[j] = b + 2 * QUADS;
        const float4* c = soa4 + (size_t)(P_ + gbase + j) * SAMPLE_F4;
        gpx[j] = c; gpy[j] = c + QUADS; gpz[j] = c + 2 * QUADS;
    }

    float acc[16];
#pragma unroll
    for (int i = 0; i < 16; ++i) acc[i] = 0.f;

    for (int q = t; q < QUADS; q += 256) {
        float4 PX[4], PY[4], PZ[4];
#pragma unroll
        for (int j = 0; j < 4; ++j) {
            PX[j] = ppx[j][q];
            PY[j] = ppy[j][q];
            PZ[j] = ppz[j][q];
        }
#pragma unroll
        for (int gg = 0; gg < 4; ++gg) {
            float4 GX = gpx[gg][q];
            float4 GY = gpy[gg][q];
            float4 GZ = gpz[gg][q];
            v2f gxy[4] = { v2(GX.x, GY.x), v2(GX.y, GY.y), v2(GX.z, GY.z), v2(GX.w, GY.w) };
            float gz[4] = { GZ.x, GZ.y, GZ.z, GZ.w };
#pragma unroll
            for (int pp = 0; pp < 4; ++pp) {
                int i = gg * 4 + pp;
                float x[4] = { PX[pp].x, PX[pp].y, PX[pp].z, PX[pp].w };
                float y[4] = { PY[pp].x, PY[pp].y, PY[pp].z, PY[pp].w };
                float z[4] = { PZ[pp].x, PZ[pp].y, PZ[pp].z, PZ[pp].w };
                float s = 0.f;
#pragma unroll
                for (int k = 0; k < 4; ++k) {
                    v2f dd = vfma(a03[i], vsplat(x[k]),
                             vfma(a14[i], vsplat(y[k]),
                             vfma(a25v[i], vsplat(z[k]), t01[i])));
                    dd = dd - gxy[k];
                    float dz = fmaf(a6[i], x[k], fmaf(a7[i], y[k], fmaf(a8v[i], z[k], t2[i]))) - gz[k];
                    v2f m = dd * dd;
                    s += __builtin_amdgcn_sqrtf(fmaf(dz, dz, m.x + m.y));
                }
                acc[i] += s;
            }
        }
    }

#pragma unroll
    for (int i = 0; i < 16; ++i) {
        float v = acc[i];
        v += __shfl_xor(v, 1);  v += __shfl_xor(v, 2);
        v += __shfl_xor(v, 4);  v += __shfl_xor(v, 8);
        v += __shfl_xor(v, 16); v += __shfl_xor(v, 32);
        acc[i] = v;
    }
    __shared__ float part[4][16];
    int lane = t & 63, wave = t >> 6;
    if (lane == 0) {
#pragma unroll
        for (int i = 0; i < 16; ++i) part[wave][i] = acc[i];
    }
    __syncthreads();
    if (t < 16) {
        float s = part[0][t] + part[1][t] + part[2][t] + part[3][t];
        int gg = t >> 2, pp = t & 3;
        ws->pair_err[(gbase + gg) * P_ + (pbase + pp)] = s / (float)M_;
    }
}

// ---------------- kernel 4: argmin over gallery + write outputs ----------------
__global__ void argmin_out(const WS* __restrict__ ws, float* __restrict__ out) {
    __shared__ float be[8][32];
    __shared__ int   bg[8][32];
    int t = threadIdx.x;
    int p = t & 31, slice = t >> 5;
    float best = 3.4e38f;
    int bi = G_;
    for (int g = slice; g < G_; g += 8) {
        float e = ws->pair_err[g * P_ + p];
        if (e < best) { best = e; bi = g; }
    }
    be[slice][p] = best;
    bg[slice][p] = bi;
    __syncthreads();
    if (t < P_) {
        float b0 = be[0][t];
        int   i0 = bg[0][t];
        for (int s = 1; s < 8; ++s) {
            float e = be[s][t];
            int   i = bg[s][t];
            if (e < b0 || (e == b0 && i < i0)) { b0 = e; i0 = i; }
        }
        out[t] = (float)i0;
        out[P_ + t] = b0;
    }
}

// ================= fallback path (original AoS kernels) =================
__global__ __launch_bounds__(256, 2) void crosscov_p(const float* __restrict__ pred,
                                                     const float* __restrict__ gt,
                                                     WS* __restrict__ ws) {
    int bx = blockIdx.x;
    int t = threadIdx.x;

    if (bx >= NB_CC) {
        int b = bx - NB_CC;
        bool isP = (b < P_);
        const float* base = isP ? pred + (size_t)b * (M_ * 3)
                                : gt + (size_t)(b - P_) * (M_ * 3);
        double sx = 0, sy = 0, sz = 0, sq = 0;
        for (int q = t; q < QUADS; q += 256) {
            const float4* p4 = (const float4*)(base + 12 * (size_t)q);
            float4 a = p4[0], c = p4[1], d = p4[2];
            sx += (double)a.x + (double)a.w + (double)c.z + (double)d.y;
            sy += (double)a.y + (double)c.x + (double)c.w + (double)d.z;
            sz += (double)a.z + (double)c.y + (double)d.x + (double)d.w;
            if (isP) {
                sq += (double)a.x * a.x + (double)a.y * a.y + (double)a.z * a.z +
                      (double)a.w * a.w + (double)c.x * c.x + (double)c.y * c.y +
                      (double)c.z * c.z + (double)c.w * c.w + (double)d.x * d.x +
                      (double)d.y * d.y + (double)d.z * d.z + (double)d.w * d.w;
            }
        }
        __shared__ double smem[4];
        double rx = block_reduce(sx, smem);
        double ry = block_reduce(sy, smem);
        double rz = block_reduce(sz, smem);
        double rq = block_reduce(sq, smem);
        if (t == 0) {
            double mx = rx / M_, my = ry / M_, mz = rz / M_;
            if (isP) {
                ws->mu_p[b][0] = (float)mx;
                ws->mu_p[b][1] = (float)my;
                ws->mu_p[b][2] = (float)mz;
                ws->var_p[b] = (float)(rq - (mx * mx + my * my + mz * mz) * (double)M_);
            } else {
                ws->mu_g[b - P_][0] = (float)mx;
                ws->mu_g[b - P_][1] = (float)my;
                ws->mu_g[b - P_][2] = (float)mz;
            }
        }
        return;
    }

    int gbase = (bx & 63) * 4;
    int pbase = (bx >> 6) * 4;
    const float* pb[4];
    const float* gb[4];
#pragma unroll
    for (int j = 0; j < 4; ++j) {
        pb[j] = pred + (size_t)(pbase + j) * (M_ * 3);
        gb[j] = gt + (size_t)(gbase + j) * (M_ * 3);
    }

    v2f a01[16], a34[16], a67[16], a25[16];
    float a8[16];
#pragma unroll
    for (int i = 0; i < 16; ++i) {
        a01[i] = vsplat(0.f); a34[i] = vsplat(0.f);
        a67[i] = vsplat(0.f); a25[i] = vsplat(0.f);
        a8[i] = 0.f;
    }

    for (int q = t; q < QUADS; q += 256) {
        float4 P[4][3];
#pragma unroll
        for (int j = 0; j < 4; ++j) {
            const float4* p4 = (const float4*)(pb[j] + 12 * (size_t)q);
            P[j][0] = p4[0]; P[j][1] = p4[1]; P[j][2] = p4[2];
        }
#pragma unroll
        for (int gg = 0; gg < 4; ++gg) {
            const float4* g4 = (const float4*)(gb[gg] + 12 * (size_t)q);
            float4 Ga = g4[0], Gc = g4[1], Gd = g4[2];
            v2f gxy0 = v2(Ga.x, Ga.y), gxy1 = v2(Ga.w, Gc.x);
            v2f gxy2 = v2(Gc.z, Gc.w), gxy3 = v2(Gd.y, Gd.z);
            float gz0 = Ga.z, gz1 = Gc.y, gz2 = Gd.x, gz3 = Gd.w;
#pragma unroll
            for (int pp = 0; pp < 4; ++pp) {
                int i = gg * 4 + pp;
                float4 Pa = P[pp][0], Pc = P[pp][1], Pd = P[pp][2];
                CC_VERT(i, Pa.x, Pa.y, Pa.z, gxy0, gz0)
                CC_VERT(i, Pa.w, Pc.x, Pc.y, gxy1, gz1)
                CC_VERT(i, Pc.z, Pc.w, Pd.x, gxy2, gz2)
                CC_VERT(i, Pd.y, Pd.z, Pd.w, gxy3, gz3)
            }
        }
    }

    float K[16][9];
#pragma unroll
    for (int i = 0; i < 16; ++i) {
        K[i][0] = a01[i].x; K[i][1] = a01[i].y; K[i][2] = a25[i].x;
        K[i][3] = a34[i].x; K[i][4] = a34[i].y; K[i][5] = a25[i].y;
        K[i][6] = a67[i].x; K[i][7] = a67[i].y; K[i][8] = a8[i];
    }
#pragma unroll
    for (int i = 0; i < 16; ++i)
#pragma unroll
        for (int j = 0; j < 9; ++j) {
            float v = K[i][j];
            v += __shfl_xor(v, 1);  v += __shfl_xor(v, 2);
            v += __shfl_xor(v, 4);  v += __shfl_xor(v, 8);
            v += __shfl_xor(v, 16); v += __shfl_xor(v, 32);
            K[i][j] = v;
        }
    __shared__ float part[4][144];
    int lane = t & 63, wave = t >> 6;
    if (lane == 0) {
#pragma unroll
        for (int i = 0; i < 16; ++i)
#pragma unroll
            for (int j = 0; j < 9; ++j) part[wave][i * 9 + j] = K[i][j];
    }
    __syncthreads();
    if (t < 144) {
        float s = part[0][t] + part[1][t] + part[2][t] + part[3][t];
        int idx = t / 9, j = t % 9;
        int gg = idx >> 2, pp = idx & 3;
        ws->Kmat[(gbase + gg) * P_ + (pbase + pp)][j] = s;
    }
}

__global__ __launch_bounds__(256, 3) void pair_error_p(const float* __restrict__ pred,
                                                       const float* __restrict__ gt,
                                                       WS* __restrict__ ws) {
    int bx = blockIdx.x;
    int gbase = (bx & 63) * 4;
    int pbase = (bx >> 6) * 2;
    int t = threadIdx.x;

    v2f a03[8], a14[8], a25v[8], t01[8];
    float a6[8], a7[8], a8v[8], t2[8];
#pragma unroll
    for (int gg = 0; gg < 4; ++gg)
#pragma unroll
        for (int pp = 0; pp < 2; ++pp) {
            int i = gg * 2 + pp;
            const float* At = ws->At[(gbase + gg) * P_ + (pbase + pp)];
            a03[i] = v2(At[0], At[3]);
            a14[i] = v2(At[1], At[4]);
            a25v[i] = v2(At[2], At[5]);
            t01[i] = v2(At[9], At[10]);
            a6[i] = At[6]; a7[i] = At[7]; a8v[i] = At[8]; t2[i] = At[11];
        }

    const float* pb0 = pred + (size_t)pbase * (M_ * 3);
    const float* pb1 = pred + (size_t)(pbase + 1) * (M_ * 3);
    const float* gb[4];
#pragma unroll
    for (int j = 0; j < 4; ++j) gb[j] = gt + (size_t)(gbase + j) * (M_ * 3);

    float acc[8];
#pragma unroll
    for (int i = 0; i < 8; ++i) acc[i] = 0.f;

    for (int q = t; q < QUADS; q += 256) {
        float4 P[2][3];
        {
            const float4* p4 = (const float4*)(pb0 + 12 * (size_t)q);
            P[0][0] = p4[0]; P[0][1] = p4[1]; P[0][2] = p4[2];
            p4 = (const float4*)(pb1 + 12 * (size_t)q);
            P[1][0] = p4[0]; P[1][1] = p4[1]; P[1][2] = p4[2];
        }
#pragma unroll
        for (int gg = 0; gg < 4; ++gg) {
            const float4* g4 = (const float4*)(gb[gg] + 12 * (size_t)q);
            float4 Ga = g4[0], Gc = g4[1], Gd = g4[2];
            v2f gxy[4] = { v2(Ga.x, Ga.y), v2(Ga.w, Gc.x), v2(Gc.z, Gc.w), v2(Gd.y, Gd.z) };
            float gz[4] = { Ga.z, Gc.y, Gd.x, Gd.w };
#pragma unroll
            for (int pp = 0; pp < 2; ++pp) {
                int i = gg * 2 + pp;
                float4 Pa = P[pp][0], Pc = P[pp][1], Pd = P[pp][2];
                float x[4] = { Pa.x, Pa.w, Pc.z, Pd.y };
                float y[4] = { Pa.y, Pc.x, Pc.w, Pd.z };
                float z[4] = { Pa.z, Pc.y, Pd.x, Pd.w };
                float s = 0.f;
#pragma unroll
                for (int k = 0; k < 4; ++k) {
                    v2f dd = vfma(a03[i], vsplat(x[k]),
                             vfma(a14[i], vsplat(y[k]),
                             vfma(a25v[i], vsplat(z[k]), t01[i])));
                    dd = dd - gxy[k];
                    float dz = fmaf(a6[i], x[k], fmaf(a7[i], y[k], fmaf(a8v[i], z[k], t2[i]))) - gz[k];
                    v2f m = dd * dd;
                    s += __builtin_amdgcn_sqrtf(fmaf(dz, dz, m.x + m.y));
                }
                acc[i] += s;
            }
        }
    }

#pragma unroll
    for (int i = 0; i < 8; ++i) {
        float v = acc[i];
        v += __shfl_xor(v, 1);  v += __shfl_xor(v, 2);
        v += __shfl_xor(v, 4);  v += __shfl_xor(v, 8);
        v += __shfl_xor(v, 16); v += __shfl_xor(v, 32);
        acc[i] = v;
    }
    __shared__ float part[4][8];
    int lane = t & 63, wave = t >> 6;
    if (lane == 0) {
#pragma unroll
        for (int i = 0; i < 8; ++i) part[wave][i] = acc[i];
    }
    __syncthreads();
    if (t < 8) {
        float s = part[0][t] + part[1][t] + part[2][t] + part[3][t];
        int gg = t >> 1, pp = t & 1;
        ws->pair_err[(gbase + gg) * P_ + (pbase + pp)] = s / (float)M_;
    }
}

extern "C" void kernel_launch(void* const* d_in, const int* in_sizes, int n_in,
                              void* d_out, int out_size, void* d_ws, size_t ws_size,
                              hipStream_t stream) {
    const float* pred = (const float*)d_in[0];   // (32, 2, 6890, 3)
    const float* gt   = (const float*)d_in[1];   // (256, 2, 6890, 3)
    float* out = (float*)d_out;                  // 64 floats: mapping(32) | min_error(32)
    WS* ws = (WS*)d_ws;

    if (ws_size >= sizeof(WS)) {
        // SoA path: repack (+stats) once, then fully-coalesced heavy kernels.
        hipMemsetAsync(d_ws, 0, sizeof(double) * SAMPLES * 4, stream);
        repack_stats<<<dim3(SAMPLES * NCHUNK), dim3(256), 0, stream>>>(pred, gt, ws);
        crosscov_soa<<<dim3(8 * 64), dim3(256), 0, stream>>>(ws);
        pair_svd<<<dim3(NPAIR / 64), dim3(64), 0, stream>>>(ws, 1);
        pair_error_soa<<<dim3(8 * 64), dim3(256), 0, stream>>>(ws);
        argmin_out<<<dim3(1), dim3(256), 0, stream>>>(ws, out);
    } else {
        // fallback: original AoS path (workspace too small for SoA copy)
        crosscov_p<<<dim3(NB_CC + P_ + G_), dim3(256), 0, stream>>>(pred, gt, ws);
        pair_svd<<<dim3(NPAIR / 64), dim3(64), 0, stream>>>(ws, 0);
        pair_error_p<<<dim3(16 * 64), dim3(256), 0, stream>>>(pred, gt, ws);
        argmin_out<<<dim3(1), dim3(256), 0, stream>>>(ws, out);
    }
}

// Round 4
// 288.194 us; speedup vs baseline: 1.9217x; 1.9217x over previous
//
#include <hip/hip_runtime.h>
#include <math.h>

#define P_ 32
#define G_ 256
#define NV 6890
#define M_ (2 * NV)          // 13780 joint points per sample
#define QUADS (M_ / 4)       // 3445 vertex-quads; also float4s per SoA plane
#define NPAIR (P_ * G_)      // 8192
#define NB_CC 512            // fallback crosscov blocks
#define SAMPLES (P_ + G_)    // 288
#define NCHUNK 14            // ceil(QUADS / 256)
#define SAMPLE_F4 (3 * QUADS) // 10335 float4 per sample

typedef float v2f __attribute__((ext_vector_type(2)));
__device__ inline v2f v2(float a, float b) { v2f r; r.x = a; r.y = b; return r; }
__device__ inline v2f vsplat(float a) { v2f r; r.x = a; r.y = a; return r; }
__device__ inline v2f vfma(v2f a, v2f b, v2f c) { return __builtin_elementwise_fma(a, b, c); }

// ---------------- workspace layout ----------------
struct WS {
    double stat[SAMPLES][4];       // atomic sums: x, y, z, (sumsq for preds)
    float soa[SAMPLES * 3 * M_];   // 47.6 MB transposed copy
    float mu_p[P_][3];             // fallback-path stats
    float var_p[P_];
    float mu_g[G_][3];
    float At[NPAIR][12];     // A = scale*R (9) then t (3); pair = g*32 + p
    float Kmat[NPAIR][9];    // cross-covariance (pre mean-subtraction)
    float pair_err[NPAIR];   // mean v2v error per pair
};

// ---------------- block reduction (valid on thread 0) ----------------
__device__ inline double block_reduce(double v, double* smem) {
#pragma unroll
    for (int off = 32; off > 0; off >>= 1) v += __shfl_down(v, off, 64);
    int wid  = threadIdx.x >> 6;
    int lane = threadIdx.x & 63;
    __syncthreads();
    if (lane == 0) smem[wid] = v;
    __syncthreads();
    double r = 0.0;
    if (threadIdx.x == 0) {
        int nw = blockDim.x >> 6;
        for (int w = 0; w < nw; ++w) r += smem[w];
    }
    return r;
}

// ---------------- kernel 0: AoS -> SoA repack + fused stats ----
__global__ __launch_bounds__(256) void repack_stats(const float* __restrict__ pred,
                                                    const float* __restrict__ gt,
                                                    WS* __restrict__ ws) {
    int bx = blockIdx.x;
    int s = bx / NCHUNK;
    int chunk = bx - s * NCHUNK;
    bool isP = (s < P_);
    const float4* src4 = (const float4*)(isP ? pred + (size_t)s * (M_ * 3)
                                             : gt + (size_t)(s - P_) * (M_ * 3));
    __shared__ __align__(16) float lds[256 * 12];   // 12 KB chunk staging
    int t = threadIdx.x;
    int f4base = chunk * (256 * 3);
#pragma unroll
    for (int k = 0; k < 3; ++k) {
        int f4 = f4base + k * 256 + t;
        if (f4 < SAMPLE_F4) ((float4*)lds)[k * 256 + t] = src4[f4];
    }
    __syncthreads();
    int q = chunk * 256 + t;
    double sx = 0, sy = 0, sz = 0, sq = 0;
    if (q < QUADS) {
        const float* v = lds + 12 * t;
        float4 X = make_float4(v[0], v[3], v[6], v[9]);
        float4 Y = make_float4(v[1], v[4], v[7], v[10]);
        float4 Z = make_float4(v[2], v[5], v[8], v[11]);
        float4* dst = (float4*)ws->soa;
        dst[(size_t)(s * 3 + 0) * QUADS + q] = X;
        dst[(size_t)(s * 3 + 1) * QUADS + q] = Y;
        dst[(size_t)(s * 3 + 2) * QUADS + q] = Z;
        sx = (double)X.x + (double)X.y + (double)X.z + (double)X.w;
        sy = (double)Y.x + (double)Y.y + (double)Y.z + (double)Y.w;
        sz = (double)Z.x + (double)Z.y + (double)Z.z + (double)Z.w;
        if (isP) {
            sq = (double)X.x * X.x + (double)X.y * X.y + (double)X.z * X.z +
                 (double)X.w * X.w + (double)Y.x * Y.x + (double)Y.y * Y.y +
                 (double)Y.z * Y.z + (double)Y.w * Y.w + (double)Z.x * Z.x +
                 (double)Z.y * Z.y + (double)Z.z * Z.z + (double)Z.w * Z.w;
        }
    }
    __shared__ double smem[4];
    double rx = block_reduce(sx, smem);
    double ry = block_reduce(sy, smem);
    double rz = block_reduce(sz, smem);
    double rq = block_reduce(sq, smem);
    if (t == 0) {
        atomicAdd(&ws->stat[s][0], rx);
        atomicAdd(&ws->stat[s][1], ry);
        atomicAdd(&ws->stat[s][2], rz);
        if (isP) atomicAdd(&ws->stat[s][3], rq);
    }
}

// ---------------- kernel 1: crosscov on SoA, 4p x 4g tiles ----------------
// 512 blocks = ptile(8)*64 + gtile(64); XCD = gtile%8. Traffic per block =
// 8 samples * 165KB -> 676 MB total. 144 acc + ~60 load floats ~= 215 VGPR.
// __launch_bounds__(256,2): VGPR cap 256 (R3 lesson: NO bounds => compiler
// clamps to 64 VGPR for 1024-thread launchability => 1.6 GB scratch spill).
#define CC_VERT(i, px, py, pz, gxy, gz)                  \
    a01[i] = vfma(vsplat(px), gxy, a01[i]);              \
    a34[i] = vfma(vsplat(py), gxy, a34[i]);              \
    a67[i] = vfma(vsplat(pz), gxy, a67[i]);              \
    a25[i] = vfma(v2(px, py), vsplat(gz), a25[i]);       \
    a8[i]  = fmaf(pz, gz, a8[i]);

__global__ __launch_bounds__(256, 2) void crosscov_soa(WS* __restrict__ ws) {
    int bx = blockIdx.x;
    int gbase = (bx & 63) * 4;
    int pbase = (bx >> 6) * 4;   // 8 ptiles
    int t = threadIdx.x;
    const float4* soa4 = (const float4*)ws->soa;

    // wave-uniform plane pointers (SGPR bases); loads index by [q] only
    const float4* ppx[4]; const float4* ppy[4]; const float4* ppz[4];
    const float4* gpx[4]; const float4* gpy[4]; const float4* gpz[4];
#pragma unroll
    for (int j = 0; j < 4; ++j) {
        const float4* b = soa4 + (size_t)(pbase + j) * SAMPLE_F4;
        ppx[j] = b; ppy[j] = b + QUADS; ppz[j] = b + 2 * QUADS;
        const float4* c = soa4 + (size_t)(P_ + gbase + j) * SAMPLE_F4;
        gpx[j] = c; gpy[j] = c + QUADS; gpz[j] = c + 2 * QUADS;
    }

    v2f a01[16], a34[16], a67[16], a25[16];
    float a8[16];
#pragma unroll
    for (int i = 0; i < 16; ++i) {
        a01[i] = vsplat(0.f); a34[i] = vsplat(0.f);
        a67[i] = vsplat(0.f); a25[i] = vsplat(0.f);
        a8[i] = 0.f;
    }

    for (int q = t; q < QUADS; q += 256) {
        float4 PX[4], PY[4], PZ[4];
#pragma unroll
        for (int j = 0; j < 4; ++j) {
            PX[j] = ppx[j][q];
            PY[j] = ppy[j][q];
            PZ[j] = ppz[j][q];
        }
#pragma unroll
        for (int gg = 0; gg < 4; ++gg) {
            float4 GX = gpx[gg][q];
            float4 GY = gpy[gg][q];
            float4 GZ = gpz[gg][q];
            v2f gxy0 = v2(GX.x, GY.x), gxy1 = v2(GX.y, GY.y);
            v2f gxy2 = v2(GX.z, GY.z), gxy3 = v2(GX.w, GY.w);
#pragma unroll
            for (int pp = 0; pp < 4; ++pp) {
                int i = gg * 4 + pp;
                CC_VERT(i, PX[pp].x, PY[pp].x, PZ[pp].x, gxy0, GZ.x)
                CC_VERT(i, PX[pp].y, PY[pp].y, PZ[pp].y, gxy1, GZ.y)
                CC_VERT(i, PX[pp].z, PY[pp].z, PZ[pp].z, gxy2, GZ.z)
                CC_VERT(i, PX[pp].w, PY[pp].w, PZ[pp].w, gxy3, GZ.w)
            }
        }
    }

    float K[16][9];
#pragma unroll
    for (int i = 0; i < 16; ++i) {
        K[i][0] = a01[i].x; K[i][1] = a01[i].y; K[i][2] = a25[i].x;
        K[i][3] = a34[i].x; K[i][4] = a34[i].y; K[i][5] = a25[i].y;
        K[i][6] = a67[i].x; K[i][7] = a67[i].y; K[i][8] = a8[i];
    }
#pragma unroll
    for (int i = 0; i < 16; ++i)
#pragma unroll
        for (int j = 0; j < 9; ++j) {
            float v = K[i][j];
            v += __shfl_xor(v, 1);  v += __shfl_xor(v, 2);
            v += __shfl_xor(v, 4);  v += __shfl_xor(v, 8);
            v += __shfl_xor(v, 16); v += __shfl_xor(v, 32);
            K[i][j] = v;
        }
    __shared__ float part[4][144];
    int lane = t & 63, wave = t >> 6;
    if (lane == 0) {
#pragma unroll
        for (int i = 0; i < 16; ++i)
#pragma unroll
            for (int j = 0; j < 9; ++j) part[wave][i * 9 + j] = K[i][j];
    }
    __syncthreads();
    if (t < 144) {
        float s = part[0][t] + part[1][t] + part[2][t] + part[3][t];
        int idx = t / 9, j = t % 9;
        int gg = idx >> 2, pp = idx & 3;
        ws->Kmat[(gbase + gg) * P_ + (pbase + pp)][j] = s;
    }
}

// ---------------- kernel 2: per-pair SVD -> A = scale*R, t ----------------
__global__ void pair_svd(WS* __restrict__ ws, int use_stat) {
    int pair = blockIdx.x * blockDim.x + threadIdx.x;
    if (pair >= NPAIR) return;
    int p = pair & 31;
    int g = pair >> 5;

    double mp[3], mg[3], varp;
    if (use_stat) {
        const double invM = 1.0 / (double)M_;
        mp[0] = ws->stat[p][0] * invM;
        mp[1] = ws->stat[p][1] * invM;
        mp[2] = ws->stat[p][2] * invM;
        mg[0] = ws->stat[P_ + g][0] * invM;
        mg[1] = ws->stat[P_ + g][1] * invM;
        mg[2] = ws->stat[P_ + g][2] * invM;
        varp = ws->stat[p][3] - (mp[0] * mp[0] + mp[1] * mp[1] + mp[2] * mp[2]) * (double)M_;
    } else {
        mp[0] = ws->mu_p[p][0]; mp[1] = ws->mu_p[p][1]; mp[2] = ws->mu_p[p][2];
        mg[0] = ws->mu_g[g][0]; mg[1] = ws->mu_g[g][1]; mg[2] = ws->mu_g[g][2];
        varp = (double)ws->var_p[p];
    }

    double K[3][3];
#pragma unroll
    for (int a = 0; a < 3; ++a)
#pragma unroll
        for (int b = 0; b < 3; ++b)
            K[a][b] = (double)ws->Kmat[pair][3 * a + b] - (double)M_ * mp[a] * mg[b];

    // S = K^T K (symmetric PSD)
    double S[3][3];
#pragma unroll
    for (int a = 0; a < 3; ++a)
#pragma unroll
        for (int b = 0; b < 3; ++b) {
            double acc = 0.0;
#pragma unroll
            for (int c = 0; c < 3; ++c) acc += K[c][a] * K[c][b];
            S[a][b] = acc;
        }

    // Jacobi eigendecomposition S = V Lambda V^T
    double V[3][3] = { {1, 0, 0}, {0, 1, 0}, {0, 0, 1} };
    double tr = S[0][0] + S[1][1] + S[2][2];
    double tol = 1e-30 * tr * tr + 1e-300;
    const int PP[3] = {0, 0, 1};
    const int QQ[3] = {1, 2, 2};
    for (int sweep = 0; sweep < 30; ++sweep) {
        double off = S[0][1] * S[0][1] + S[0][2] * S[0][2] + S[1][2] * S[1][2];
        if (off <= tol) break;
        for (int r3 = 0; r3 < 3; ++r3) {
            int pq = PP[r3], qq = QQ[r3];
            double apq = S[pq][qq];
            if (apq == 0.0) continue;
            double theta = (S[qq][qq] - S[pq][pq]) / (2.0 * apq);
            double tt = copysign(1.0, theta) / (fabs(theta) + sqrt(theta * theta + 1.0));
            double c = 1.0 / sqrt(tt * tt + 1.0);
            double sj = tt * c;
            for (int r = 0; r < 3; ++r) {
                double srp = S[r][pq], srq = S[r][qq];
                S[r][pq] = c * srp - sj * srq;
                S[r][qq] = sj * srp + c * srq;
            }
            for (int cc = 0; cc < 3; ++cc) {
                double spr = S[pq][cc], sqr = S[qq][cc];
                S[pq][cc] = c * spr - sj * sqr;
                S[qq][cc] = sj * spr + c * sqr;
            }
            for (int r = 0; r < 3; ++r) {
                double vrp = V[r][pq], vrq = V[r][qq];
                V[r][pq] = c * vrp - sj * vrq;
                V[r][qq] = sj * vrp + c * vrq;
            }
        }
    }

    double lam[3] = { S[0][0], S[1][1], S[2][2] };
    int idx[3] = { 0, 1, 2 };
    if (lam[idx[0]] < lam[idx[1]]) { int tt = idx[0]; idx[0] = idx[1]; idx[1] = tt; }
    if (lam[idx[0]] < lam[idx[2]]) { int tt = idx[0]; idx[0] = idx[2]; idx[2] = tt; }
    if (lam[idx[1]] < lam[idx[2]]) { int tt = idx[1]; idx[1] = idx[2]; idx[2] = tt; }
    double Vs[3][3];
    double sv[3];
#pragma unroll
    for (int i = 0; i < 3; ++i) {
        double l = lam[idx[i]];
        sv[i] = sqrt(l > 0.0 ? l : 0.0);
        for (int r = 0; r < 3; ++r) Vs[r][i] = V[r][idx[i]];
    }

    double U[3][3];
#pragma unroll
    for (int i = 0; i < 3; ++i) {
        double kx = K[0][0] * Vs[0][i] + K[0][1] * Vs[1][i] + K[0][2] * Vs[2][i];
        double ky = K[1][0] * Vs[0][i] + K[1][1] * Vs[1][i] + K[1][2] * Vs[2][i];
        double kz = K[2][0] * Vs[0][i] + K[2][1] * Vs[1][i] + K[2][2] * Vs[2][i];
        double inv = (sv[i] > 1e-12 * sv[0] && sv[i] > 0.0) ? 1.0 / sv[i] : 0.0;
        U[0][i] = kx * inv; U[1][i] = ky * inv; U[2][i] = kz * inv;
    }
    if (sv[2] <= 1e-12 * sv[0] || sv[0] == 0.0) {
        U[0][2] = U[1][0] * U[2][1] - U[2][0] * U[1][1];
        U[1][2] = U[2][0] * U[0][1] - U[0][0] * U[2][1];
        U[2][2] = U[0][0] * U[1][1] - U[1][0] * U[0][1];
    }

    double detK = K[0][0] * (K[1][1] * K[2][2] - K[1][2] * K[2][1])
                - K[0][1] * (K[1][0] * K[2][2] - K[1][2] * K[2][0])
                + K[0][2] * (K[1][0] * K[2][1] - K[1][1] * K[2][0]);
    double d = (detK >= 0.0) ? 1.0 : -1.0;
    double scale = (sv[0] + sv[1] + d * sv[2]) / varp;

    float A[9];
#pragma unroll
    for (int a = 0; a < 3; ++a)
#pragma unroll
        for (int b = 0; b < 3; ++b) {
            double r = Vs[a][0] * U[b][0] + Vs[a][1] * U[b][1] + d * Vs[a][2] * U[b][2];
            A[3 * a + b] = (float)(scale * r);
        }
    float tvec[3];
#pragma unroll
    for (int a = 0; a < 3; ++a)
        tvec[a] = (float)(mg[a] - ((double)A[3 * a + 0] * mp[0] + (double)A[3 * a + 1] * mp[1] +
                                   (double)A[3 * a + 2] * mp[2]));

#pragma unroll
    for (int j = 0; j < 9; ++j) ws->At[pair][j] = A[j];
#pragma unroll
    for (int j = 0; j < 3; ++j) ws->At[pair][9 + j] = tvec[j];
}

// ---------------- kernel 3: v2v error on SoA (4p x 4g) ---------
// 512 blocks. 192 At floats block-uniform (SGPR+VGPR) + 48 load + 16 acc.
// __launch_bounds__(256,2): VGPR cap 256 (same R3 lesson).
__global__ __launch_bounds__(256, 2) void pair_error_soa(WS* __restrict__ ws) {
    int bx = blockIdx.x;
    int gbase = (bx & 63) * 4;
    int pbase = (bx >> 6) * 4;
    int t = threadIdx.x;

    v2f a03[16], a14[16], a25v[16], t01[16];
    float a6[16], a7[16], a8v[16], t2[16];
#pragma unroll
    for (int gg = 0; gg < 4; ++gg)
#pragma unroll
        for (int pp = 0; pp < 4; ++pp) {
            int i = gg * 4 + pp;
            const float* At = ws->At[(gbase + gg) * P_ + (pbase + pp)];
            a03[i] = v2(At[0], At[3]);
            a14[i] = v2(At[1], At[4]);
            a25v[i] = v2(At[2], At[5]);
            t01[i] = v2(At[9], At[10]);
            a6[i] = At[6]; a7[i] = At[7]; a8v[i] = At[8]; t2[i] = At[11];
        }

    const float4* soa4 = (const float4*)ws->soa;
    const float4* ppx[4]; const float4* ppy[4]; const float4* ppz[4];
    const float4* gpx[4]; const float4* gpy[4]; const float4* gpz[4];
#pragma unroll
    for (int j = 0; j < 4; ++j) {
        const float4* b = soa4 + (size_t)(pbase + j) * SAMPLE_F4;
        ppx[j] = b; ppy[j] = b + QUADS; ppz[j] = b + 2 * QUADS;
        const float4* c = soa4 + (size_t)(P_ + gbase + j) * SAMPLE_F4;
        gpx[j] = c; gpy[j] = c + QUADS; gpz[j] = c + 2 * QUADS;
    }

    float acc[16];
#pragma unroll
    for (int i = 0; i < 16; ++i) acc[i] = 0.f;

    for (int q = t; q < QUADS; q += 256) {
        float4 PX[4], PY[4], PZ[4];
#pragma unroll
        for (int j = 0; j < 4; ++j) {
            PX[j] = ppx[j][q];
            PY[j] = ppy[j][q];
            PZ[j] = ppz[j][q];
        }
#pragma unroll
        for (int gg = 0; gg < 4; ++gg) {
            float4 GX = gpx[gg][q];
            float4 GY = gpy[gg][q];
            float4 GZ = gpz[gg][q];
            v2f gxy[4] = { v2(GX.x, GY.x), v2(GX.y, GY.y), v2(GX.z, GY.z), v2(GX.w, GY.w) };
            float gz[4] = { GZ.x, GZ.y, GZ.z, GZ.w };
#pragma unroll
            for (int pp = 0; pp < 4; ++pp) {
                int i = gg * 4 + pp;
                float x[4] = { PX[pp].x, PX[pp].y, PX[pp].z, PX[pp].w };
                float y[4] = { PY[pp].x, PY[pp].y, PY[pp].z, PY[pp].w };
                float z[4] = { PZ[pp].x, PZ[pp].y, PZ[pp].z, PZ[pp].w };
                float s = 0.f;
#pragma unroll
                for (int k = 0; k < 4; ++k) {
                    v2f dd = vfma(a03[i], vsplat(x[k]),
                             vfma(a14[i], vsplat(y[k]),
                             vfma(a25v[i], vsplat(z[k]), t01[i])));
                    dd = dd - gxy[k];
                    float dz = fmaf(a6[i], x[k], fmaf(a7[i], y[k], fmaf(a8v[i], z[k], t2[i]))) - gz[k];
                    v2f m = dd * dd;
                    s += __builtin_amdgcn_sqrtf(fmaf(dz, dz, m.x + m.y));
                }
                acc[i] += s;
            }
        }
    }

#pragma unroll
    for (int i = 0; i < 16; ++i) {
        float v = acc[i];
        v += __shfl_xor(v, 1);  v += __shfl_xor(v, 2);
        v += __shfl_xor(v, 4);  v += __shfl_xor(v, 8);
        v += __shfl_xor(v, 16); v += __shfl_xor(v, 32);
        acc[i] = v;
    }
    __shared__ float part[4][16];
    int lane = t & 63, wave = t >> 6;
    if (lane == 0) {
#pragma unroll
        for (int i = 0; i < 16; ++i) part[wave][i] = acc[i];
    }
    __syncthreads();
    if (t < 16) {
        float s = part[0][t] + part[1][t] + part[2][t] + part[3][t];
        int gg = t >> 2, pp = t & 3;
        ws->pair_err[(gbase + gg) * P_ + (pbase + pp)] = s / (float)M_;
    }
}

// ---------------- kernel 4: argmin over gallery + write outputs ----------------
__global__ void argmin_out(const WS* __restrict__ ws, float* __restrict__ out) {
    __shared__ float be[8][32];
    __shared__ int   bg[8][32];
    int t = threadIdx.x;
    int p = t & 31, slice = t >> 5;
    float best = 3.4e38f;
    int bi = G_;
    for (int g = slice; g < G_; g += 8) {
        float e = ws->pair_err[g * P_ + p];
        if (e < best) { best = e; bi = g; }
    }
    be[slice][p] = best;
    bg[slice][p] = bi;
    __syncthreads();
    if (t < P_) {
        float b0 = be[0][t];
        int   i0 = bg[0][t];
        for (int s = 1; s < 8; ++s) {
            float e = be[s][t];
            int   i = bg[s][t];
            if (e < b0 || (e == b0 && i < i0)) { b0 = e; i0 = i; }
        }
        out[t] = (float)i0;
        out[P_ + t] = b0;
    }
}

// ================= fallback path (original AoS kernels) =================
__global__ __launch_bounds__(256, 2) void crosscov_p(const float* __restrict__ pred,
                                                     const float* __restrict__ gt,
                                                     WS* __restrict__ ws) {
    int bx = blockIdx.x;
    int t = threadIdx.x;

    if (bx >= NB_CC) {
        int b = bx - NB_CC;
        bool isP = (b < P_);
        const float* base = isP ? pred + (size_t)b * (M_ * 3)
                                : gt + (size_t)(b - P_) * (M_ * 3);
        double sx = 0, sy = 0, sz = 0, sq = 0;
        for (int q = t; q < QUADS; q += 256) {
            const float4* p4 = (const float4*)(base + 12 * (size_t)q);
            float4 a = p4[0], c = p4[1], d = p4[2];
            sx += (double)a.x + (double)a.w + (double)c.z + (double)d.y;
            sy += (double)a.y + (double)c.x + (double)c.w + (double)d.z;
            sz += (double)a.z + (double)c.y + (double)d.x + (double)d.w;
            if (isP) {
                sq += (double)a.x * a.x + (double)a.y * a.y + (double)a.z * a.z +
                      (double)a.w * a.w + (double)c.x * c.x + (double)c.y * c.y +
                      (double)c.z * c.z + (double)c.w * c.w + (double)d.x * d.x +
                      (double)d.y * d.y + (double)d.z * d.z + (double)d.w * d.w;
            }
        }
        __shared__ double smem[4];
        double rx = block_reduce(sx, smem);
        double ry = block_reduce(sy, smem);
        double rz = block_reduce(sz, smem);
        double rq = block_reduce(sq, smem);
        if (t == 0) {
            double mx = rx / M_, my = ry / M_, mz = rz / M_;
            if (isP) {
                ws->mu_p[b][0] = (float)mx;
                ws->mu_p[b][1] = (float)my;
                ws->mu_p[b][2] = (float)mz;
                ws->var_p[b] = (float)(rq - (mx * mx + my * my + mz * mz) * (double)M_);
            } else {
                ws->mu_g[b - P_][0] = (float)mx;
                ws->mu_g[b - P_][1] = (float)my;
                ws->mu_g[b - P_][2] = (float)mz;
            }
        }
        return;
    }

    int gbase = (bx & 63) * 4;
    int pbase = (bx >> 6) * 4;
    const float* pb[4];
    const float* gb[4];
#pragma unroll
    for (int j = 0; j < 4; ++j) {
        pb[j] = pred + (size_t)(pbase + j) * (M_ * 3);
        gb[j] = gt + (size_t)(gbase + j) * (M_ * 3);
    }

    v2f a01[16], a34[16], a67[16], a25[16];
    float a8[16];
#pragma unroll
    for (int i = 0; i < 16; ++i) {
        a01[i] = vsplat(0.f); a34[i] = vsplat(0.f);
        a67[i] = vsplat(0.f); a25[i] = vsplat(0.f);
        a8[i] = 0.f;
    }

    for (int q = t; q < QUADS; q += 256) {
        float4 P[4][3];
#pragma unroll
        for (int j = 0; j < 4; ++j) {
            const float4* p4 = (const float4*)(pb[j] + 12 * (size_t)q);
            P[j][0] = p4[0]; P[j][1] = p4[1]; P[j][2] = p4[2];
        }
#pragma unroll
        for (int gg = 0; gg < 4; ++gg) {
            const float4* g4 = (const float4*)(gb[gg] + 12 * (size_t)q);
            float4 Ga = g4[0], Gc = g4[1], Gd = g4[2];
            v2f gxy0 = v2(Ga.x, Ga.y), gxy1 = v2(Ga.w, Gc.x);
            v2f gxy2 = v2(Gc.z, Gc.w), gxy3 = v2(Gd.y, Gd.z);
            float gz0 = Ga.z, gz1 = Gc.y, gz2 = Gd.x, gz3 = Gd.w;
#pragma unroll
            for (int pp = 0; pp < 4; ++pp) {
                int i = gg * 4 + pp;
                float4 Pa = P[pp][0], Pc = P[pp][1], Pd = P[pp][2];
                CC_VERT(i, Pa.x, Pa.y, Pa.z, gxy0, gz0)
                CC_VERT(i, Pa.w, Pc.x, Pc.y, gxy1, gz1)
                CC_VERT(i, Pc.z, Pc.w, Pd.x, gxy2, gz2)
                CC_VERT(i, Pd.y, Pd.z, Pd.w, gxy3, gz3)
            }
        }
    }

    float K[16][9];
#pragma unroll
    for (int i = 0; i < 16; ++i) {
        K[i][0] = a01[i].x; K[i][1] = a01[i].y; K[i][2] = a25[i].x;
        K[i][3] = a34[i].x; K[i][4] = a34[i].y; K[i][5] = a25[i].y;
        K[i][6] = a67[i].x; K[i][7] = a67[i].y; K[i][8] = a8[i];
    }
#pragma unroll
    for (int i = 0; i < 16; ++i)
#pragma unroll
        for (int j = 0; j < 9; ++j) {
            float v = K[i][j];
            v += __shfl_xor(v, 1);  v += __shfl_xor(v, 2);
            v += __shfl_xor(v, 4);  v += __shfl_xor(v, 8);
            v += __shfl_xor(v, 16); v += __shfl_xor(v, 32);
            K[i][j] = v;
        }
    __shared__ float part[4][144];
    int lane = t & 63, wave = t >> 6;
    if (lane == 0) {
#pragma unroll
        for (int i = 0; i < 16; ++i)
#pragma unroll
            for (int j = 0; j < 9; ++j) part[wave][i * 9 + j] = K[i][j];
    }
    __syncthreads();
    if (t < 144) {
        float s = part[0][t] + part[1][t] + part[2][t] + part[3][t];
        int idx = t / 9, j = t % 9;
        int gg = idx >> 2, pp = idx & 3;
        ws->Kmat[(gbase + gg) * P_ + (pbase + pp)][j] = s;
    }
}

__global__ __launch_bounds__(256, 3) void pair_error_p(const float* __restrict__ pred,
                                                       const float* __restrict__ gt,
                                                       WS* __restrict__ ws) {
    int bx = blockIdx.x;
    int gbase = (bx & 63) * 4;
    int pbase = (bx >> 6) * 2;
    int t = threadIdx.x;

    v2f a03[8], a14[8], a25v[8], t01[8];
    float a6[8], a7[8], a8v[8], t2[8];
#pragma unroll
    for (int gg = 0; gg < 4; ++gg)
#pragma unroll
        for (int pp = 0; pp < 2; ++pp) {
            int i = gg * 2 + pp;
            const float* At = ws->At[(gbase + gg) * P_ + (pbase + pp)];
            a03[i] = v2(At[0], At[3]);
            a14[i] = v2(At[1], At[4]);
            a25v[i] = v2(At[2], At[5]);
            t01[i] = v2(At[9], At[10]);
            a6[i] = At[6]; a7[i] = At[7]; a8v[i] = At[8]; t2[i] = At[11];
        }

    const float* pb0 = pred + (size_t)pbase * (M_ * 3);
    const float* pb1 = pred + (size_t)(pbase + 1) * (M_ * 3);
    const float* gb[4];
#pragma unroll
    for (int j = 0; j < 4; ++j) gb[j] = gt + (size_t)(gbase + j) * (M_ * 3);

    float acc[8];
#pragma unroll
    for (int i = 0; i < 8; ++i) acc[i] = 0.f;

    for (int q = t; q < QUADS; q += 256) {
        float4 P[2][3];
        {
            const float4* p4 = (const float4*)(pb0 + 12 * (size_t)q);
            P[0][0] = p4[0]; P[0][1] = p4[1]; P[0][2] = p4[2];
            p4 = (const float4*)(pb1 + 12 * (size_t)q);
            P[1][0] = p4[0]; P[1][1] = p4[1]; P[1][2] = p4[2];
        }
#pragma unroll
        for (int gg = 0; gg < 4; ++gg) {
            const float4* g4 = (const float4*)(gb[gg] + 12 * (size_t)q);
            float4 Ga = g4[0], Gc = g4[1], Gd = g4[2];
            v2f gxy[4] = { v2(Ga.x, Ga.y), v2(Ga.w, Gc.x), v2(Gc.z, Gc.w), v2(Gd.y, Gd.z) };
            float gz[4] = { Ga.z, Gc.y, Gd.x, Gd.w };
#pragma unroll
            for (int pp = 0; pp < 2; ++pp) {
                int i = gg * 2 + pp;
                float4 Pa = P[pp][0], Pc = P[pp][1], Pd = P[pp][2];
                float x[4] = { Pa.x, Pa.w, Pc.z, Pd.y };
                float y[4] = { Pa.y, Pc.x, Pc.w, Pd.z };
                float z[4] = { Pa.z, Pc.y, Pd.x, Pd.w };
                float s = 0.f;
#pragma unroll
                for (int k = 0; k < 4; ++k) {
                    v2f dd = vfma(a03[i], vsplat(x[k]),
                             vfma(a14[i], vsplat(y[k]),
                             vfma(a25v[i], vsplat(z[k]), t01[i])));
                    dd = dd - gxy[k];
                    float dz = fmaf(a6[i], x[k], fmaf(a7[i], y[k], fmaf(a8v[i], z[k], t2[i]))) - gz[k];
                    v2f m = dd * dd;
                    s += __builtin_amdgcn_sqrtf(fmaf(dz, dz, m.x + m.y));
                }
                acc[i] += s;
            }
        }
    }

#pragma unroll
    for (int i = 0; i < 8; ++i) {
        float v = acc[i];
        v += __shfl_xor(v, 1);  v += __shfl_xor(v, 2);
        v += __shfl_xor(v, 4);  v += __shfl_xor(v, 8);
        v += __shfl_xor(v, 16); v += __shfl_xor(v, 32);
        acc[i] = v;
    }
    __shared__ float part[4][8];
    int lane = t & 63, wave = t >> 6;
    if (lane == 0) {
#pragma unroll
        for (int i = 0; i < 8; ++i) part[wave][i] = acc[i];
    }
    __syncthreads();
    if (t < 8) {
        float s = part[0][t] + part[1][t] + part[2][t] + part[3][t];
        int gg = t >> 1, pp = t & 1;
        ws->pair_err[(gbase + gg) * P_ + (pbase + pp)] = s / (float)M_;
    }
}

extern "C" void kernel_launch(void* const* d_in, const int* in_sizes, int n_in,
                              void* d_out, int out_size, void* d_ws, size_t ws_size,
                              hipStream_t stream) {
    const float* pred = (const float*)d_in[0];   // (32, 2, 6890, 3)
    const float* gt   = (const float*)d_in[1];   // (256, 2, 6890, 3)
    float* out = (float*)d_out;                  // 64 floats: mapping(32) | min_error(32)
    WS* ws = (WS*)d_ws;

    if (ws_size >= sizeof(WS)) {
        // SoA path: repack (+stats) once, then fully-coalesced heavy kernels.
        hipMemsetAsync(d_ws, 0, sizeof(double) * SAMPLES * 4, stream);
        repack_stats<<<dim3(SAMPLES * NCHUNK), dim3(256), 0, stream>>>(pred, gt, ws);
        crosscov_soa<<<dim3(8 * 64), dim3(256), 0, stream>>>(ws);
        pair_svd<<<dim3(NPAIR / 64), dim3(64), 0, stream>>>(ws, 1);
        pair_error_soa<<<dim3(8 * 64), dim3(256), 0, stream>>>(ws);
        argmin_out<<<dim3(1), dim3(256), 0, stream>>>(ws, out);
    } else {
        // fallback: original AoS path (workspace too small for SoA copy)
        crosscov_p<<<dim3(NB_CC + P_ + G_), dim3(256), 0, stream>>>(pred, gt, ws);
        pair_svd<<<dim3(NPAIR / 64), dim3(64), 0, stream>>>(ws, 0);
        pair_error_p<<<dim3(16 * 64), dim3(256), 0, stream>>>(pred, gt, ws);
        argmin_out<<<dim3(1), dim3(256), 0, stream>>>(ws, out);
    }
}

// Round 5
// 264.096 us; speedup vs baseline: 2.0970x; 1.0912x over previous
//
#include <hip/hip_runtime.h>
#include <math.h>

#define P_ 32
#define G_ 256
#define NV 6890
#define M_ (2 * NV)          // 13780 joint points per sample
#define QUADS (M_ / 4)       // 3445 vertex-quads; also float4s per SoA plane
#define NPAIR (P_ * G_)      // 8192
#define NB_CC 512            // fallback crosscov blocks
#define SAMPLES (P_ + G_)    // 288
#define NCHUNK 14            // ceil(QUADS / 256)
#define SAMPLE_F4 (3 * QUADS) // 10335 float4 per sample

typedef float v2f __attribute__((ext_vector_type(2)));
__device__ inline v2f v2(float a, float b) { v2f r; r.x = a; r.y = b; return r; }
__device__ inline v2f vsplat(float a) { v2f r; r.x = a; r.y = a; return r; }
__device__ inline v2f vfma(v2f a, v2f b, v2f c) { return __builtin_elementwise_fma(a, b, c); }

// ---------------- workspace layout ----------------
struct WS {
    double stat[SAMPLES][4];       // atomic sums: x, y, z, (sumsq for preds)
    float soa[SAMPLES * 3 * M_];   // 47.6 MB transposed copy
    float mu_p[P_][3];             // fallback-path stats
    float var_p[P_];
    float mu_g[G_][3];
    float At[NPAIR][12];     // A = scale*R (9) then t (3); pair = g*32 + p
    float Kmat[NPAIR][9];    // cross-covariance (pre mean-subtraction)
    float pair_err[NPAIR];   // mean v2v error per pair
};

// ---------------- block reduction (valid on thread 0) ----------------
__device__ inline double block_reduce(double v, double* smem) {
#pragma unroll
    for (int off = 32; off > 0; off >>= 1) v += __shfl_down(v, off, 64);
    int wid  = threadIdx.x >> 6;
    int lane = threadIdx.x & 63;
    __syncthreads();
    if (lane == 0) smem[wid] = v;
    __syncthreads();
    double r = 0.0;
    if (threadIdx.x == 0) {
        int nw = blockDim.x >> 6;
        for (int w = 0; w < nw; ++w) r += smem[w];
    }
    return r;
}

// ---------------- kernel 0: AoS -> SoA repack + fused stats ----
__global__ __launch_bounds__(256) void repack_stats(const float* __restrict__ pred,
                                                    const float* __restrict__ gt,
                                                    WS* __restrict__ ws) {
    int bx = blockIdx.x;
    int s = bx / NCHUNK;
    int chunk = bx - s * NCHUNK;
    bool isP = (s < P_);
    const float4* src4 = (const float4*)(isP ? pred + (size_t)s * (M_ * 3)
                                             : gt + (size_t)(s - P_) * (M_ * 3));
    __shared__ __align__(16) float lds[256 * 12];   // 12 KB chunk staging
    int t = threadIdx.x;
    int f4base = chunk * (256 * 3);
#pragma unroll
    for (int k = 0; k < 3; ++k) {
        int f4 = f4base + k * 256 + t;
        if (f4 < SAMPLE_F4) ((float4*)lds)[k * 256 + t] = src4[f4];
    }
    __syncthreads();
    int q = chunk * 256 + t;
    double sx = 0, sy = 0, sz = 0, sq = 0;
    if (q < QUADS) {
        const float* v = lds + 12 * t;
        float4 X = make_float4(v[0], v[3], v[6], v[9]);
        float4 Y = make_float4(v[1], v[4], v[7], v[10]);
        float4 Z = make_float4(v[2], v[5], v[8], v[11]);
        float4* dst = (float4*)ws->soa;
        dst[(size_t)(s * 3 + 0) * QUADS + q] = X;
        dst[(size_t)(s * 3 + 1) * QUADS + q] = Y;
        dst[(size_t)(s * 3 + 2) * QUADS + q] = Z;
        sx = (double)X.x + (double)X.y + (double)X.z + (double)X.w;
        sy = (double)Y.x + (double)Y.y + (double)Y.z + (double)Y.w;
        sz = (double)Z.x + (double)Z.y + (double)Z.z + (double)Z.w;
        if (isP) {
            sq = (double)X.x * X.x + (double)X.y * X.y + (double)X.z * X.z +
                 (double)X.w * X.w + (double)Y.x * Y.x + (double)Y.y * Y.y +
                 (double)Y.z * Y.z + (double)Y.w * Y.w + (double)Z.x * Z.x +
                 (double)Z.y * Z.y + (double)Z.z * Z.z + (double)Z.w * Z.w;
        }
    }
    __shared__ double smem[4];
    double rx = block_reduce(sx, smem);
    double ry = block_reduce(sy, smem);
    double rz = block_reduce(sz, smem);
    double rq = block_reduce(sq, smem);
    if (t == 0) {
        atomicAdd(&ws->stat[s][0], rx);
        atomicAdd(&ws->stat[s][1], ry);
        atomicAdd(&ws->stat[s][2], rz);
        if (isP) atomicAdd(&ws->stat[s][3], rq);
    }
}

// ---------------- kernel 1: crosscov on SoA, 4p x 4g tiles ----------------
// 512 blocks = ptile(8)*64 + gtile(64); XCD = gtile%8. Traffic per block =
// 8 samples * 165KB -> 676 MB total. 144 acc + ~60 load floats ~= 215 VGPR.
// VGPR-cap empirics on this toolchain: no bounds -> 64 cap; (256,2) -> 128
// cap (212 MB spill, R1/R4); (256) single-arg -> NATURAL allocation (R2:
// 80 = exactly the need). So: single-arg only.
#define CC_VERT(i, px, py, pz, gxy, gz)                  \
    a01[i] = vfma(vsplat(px), gxy, a01[i]);              \
    a34[i] = vfma(vsplat(py), gxy, a34[i]);              \
    a67[i] = vfma(vsplat(pz), gxy, a67[i]);              \
    a25[i] = vfma(v2(px, py), vsplat(gz), a25[i]);       \
    a8[i]  = fmaf(pz, gz, a8[i]);

__global__ __launch_bounds__(256) void crosscov_soa(WS* __restrict__ ws) {
    int bx = blockIdx.x;
    int gbase = (bx & 63) * 4;
    int pbase = (bx >> 6) * 4;   // 8 ptiles
    int t = threadIdx.x;
    const float4* soa4 = (const float4*)ws->soa;

    // wave-uniform plane pointers (SGPR bases); loads index by [q] only
    const float4* ppx[4]; const float4* ppy[4]; const float4* ppz[4];
    const float4* gpx[4]; const float4* gpy[4]; const float4* gpz[4];
#pragma unroll
    for (int j = 0; j < 4; ++j) {
        const float4* b = soa4 + (size_t)(pbase + j) * SAMPLE_F4;
        ppx[j] = b; ppy[j] = b + QUADS; ppz[j] = b + 2 * QUADS;
        const float4* c = soa4 + (size_t)(P_ + gbase + j) * SAMPLE_F4;
        gpx[j] = c; gpy[j] = c + QUADS; gpz[j] = c + 2 * QUADS;
    }

    v2f a01[16], a34[16], a67[16], a25[16];
    float a8[16];
#pragma unroll
    for (int i = 0; i < 16; ++i) {
        a01[i] = vsplat(0.f); a34[i] = vsplat(0.f);
        a67[i] = vsplat(0.f); a25[i] = vsplat(0.f);
        a8[i] = 0.f;
    }

    for (int q = t; q < QUADS; q += 256) {
        float4 PX[4], PY[4], PZ[4];
#pragma unroll
        for (int j = 0; j < 4; ++j) {
            PX[j] = ppx[j][q];
            PY[j] = ppy[j][q];
            PZ[j] = ppz[j][q];
        }
#pragma unroll
        for (int gg = 0; gg < 4; ++gg) {
            float4 GX = gpx[gg][q];
            float4 GY = gpy[gg][q];
            float4 GZ = gpz[gg][q];
            v2f gxy0 = v2(GX.x, GY.x), gxy1 = v2(GX.y, GY.y);
            v2f gxy2 = v2(GX.z, GY.z), gxy3 = v2(GX.w, GY.w);
#pragma unroll
            for (int pp = 0; pp < 4; ++pp) {
                int i = gg * 4 + pp;
                CC_VERT(i, PX[pp].x, PY[pp].x, PZ[pp].x, gxy0, GZ.x)
                CC_VERT(i, PX[pp].y, PY[pp].y, PZ[pp].y, gxy1, GZ.y)
                CC_VERT(i, PX[pp].z, PY[pp].z, PZ[pp].z, gxy2, GZ.z)
                CC_VERT(i, PX[pp].w, PY[pp].w, PZ[pp].w, gxy3, GZ.w)
            }
        }
    }

    float K[16][9];
#pragma unroll
    for (int i = 0; i < 16; ++i) {
        K[i][0] = a01[i].x; K[i][1] = a01[i].y; K[i][2] = a25[i].x;
        K[i][3] = a34[i].x; K[i][4] = a34[i].y; K[i][5] = a25[i].y;
        K[i][6] = a67[i].x; K[i][7] = a67[i].y; K[i][8] = a8[i];
    }
#pragma unroll
    for (int i = 0; i < 16; ++i)
#pragma unroll
        for (int j = 0; j < 9; ++j) {
            float v = K[i][j];
            v += __shfl_xor(v, 1);  v += __shfl_xor(v, 2);
            v += __shfl_xor(v, 4);  v += __shfl_xor(v, 8);
            v += __shfl_xor(v, 16); v += __shfl_xor(v, 32);
            K[i][j] = v;
        }
    __shared__ float part[4][144];
    int lane = t & 63, wave = t >> 6;
    if (lane == 0) {
#pragma unroll
        for (int i = 0; i < 16; ++i)
#pragma unroll
            for (int j = 0; j < 9; ++j) part[wave][i * 9 + j] = K[i][j];
    }
    __syncthreads();
    if (t < 144) {
        float s = part[0][t] + part[1][t] + part[2][t] + part[3][t];
        int idx = t / 9, j = t % 9;
        int gg = idx >> 2, pp = idx & 3;
        ws->Kmat[(gbase + gg) * P_ + (pbase + pp)][j] = s;
    }
}

// ---------------- kernel 2: per-pair SVD -> A = scale*R, t ----------------
__global__ void pair_svd(WS* __restrict__ ws, int use_stat) {
    int pair = blockIdx.x * blockDim.x + threadIdx.x;
    if (pair >= NPAIR) return;
    int p = pair & 31;
    int g = pair >> 5;

    double mp[3], mg[3], varp;
    if (use_stat) {
        const double invM = 1.0 / (double)M_;
        mp[0] = ws->stat[p][0] * invM;
        mp[1] = ws->stat[p][1] * invM;
        mp[2] = ws->stat[p][2] * invM;
        mg[0] = ws->stat[P_ + g][0] * invM;
        mg[1] = ws->stat[P_ + g][1] * invM;
        mg[2] = ws->stat[P_ + g][2] * invM;
        varp = ws->stat[p][3] - (mp[0] * mp[0] + mp[1] * mp[1] + mp[2] * mp[2]) * (double)M_;
    } else {
        mp[0] = ws->mu_p[p][0]; mp[1] = ws->mu_p[p][1]; mp[2] = ws->mu_p[p][2];
        mg[0] = ws->mu_g[g][0]; mg[1] = ws->mu_g[g][1]; mg[2] = ws->mu_g[g][2];
        varp = (double)ws->var_p[p];
    }

    double K[3][3];
#pragma unroll
    for (int a = 0; a < 3; ++a)
#pragma unroll
        for (int b = 0; b < 3; ++b)
            K[a][b] = (double)ws->Kmat[pair][3 * a + b] - (double)M_ * mp[a] * mg[b];

    // S = K^T K (symmetric PSD)
    double S[3][3];
#pragma unroll
    for (int a = 0; a < 3; ++a)
#pragma unroll
        for (int b = 0; b < 3; ++b) {
            double acc = 0.0;
#pragma unroll
            for (int c = 0; c < 3; ++c) acc += K[c][a] * K[c][b];
            S[a][b] = acc;
        }

    // Jacobi eigendecomposition S = V Lambda V^T
    double V[3][3] = { {1, 0, 0}, {0, 1, 0}, {0, 0, 1} };
    double tr = S[0][0] + S[1][1] + S[2][2];
    double tol = 1e-30 * tr * tr + 1e-300;
    const int PP[3] = {0, 0, 1};
    const int QQ[3] = {1, 2, 2};
    for (int sweep = 0; sweep < 30; ++sweep) {
        double off = S[0][1] * S[0][1] + S[0][2] * S[0][2] + S[1][2] * S[1][2];
        if (off <= tol) break;
        for (int r3 = 0; r3 < 3; ++r3) {
            int pq = PP[r3], qq = QQ[r3];
            double apq = S[pq][qq];
            if (apq == 0.0) continue;
            double theta = (S[qq][qq] - S[pq][pq]) / (2.0 * apq);
            double tt = copysign(1.0, theta) / (fabs(theta) + sqrt(theta * theta + 1.0));
            double c = 1.0 / sqrt(tt * tt + 1.0);
            double sj = tt * c;
            for (int r = 0; r < 3; ++r) {
                double srp = S[r][pq], srq = S[r][qq];
                S[r][pq] = c * srp - sj * srq;
                S[r][qq] = sj * srp + c * srq;
            }
            for (int cc = 0; cc < 3; ++cc) {
                double spr = S[pq][cc], sqr = S[qq][cc];
                S[pq][cc] = c * spr - sj * sqr;
                S[qq][cc] = sj * spr + c * sqr;
            }
            for (int r = 0; r < 3; ++r) {
                double vrp = V[r][pq], vrq = V[r][qq];
                V[r][pq] = c * vrp - sj * vrq;
                V[r][qq] = sj * vrp + c * vrq;
            }
        }
    }

    double lam[3] = { S[0][0], S[1][1], S[2][2] };
    int idx[3] = { 0, 1, 2 };
    if (lam[idx[0]] < lam[idx[1]]) { int tt = idx[0]; idx[0] = idx[1]; idx[1] = tt; }
    if (lam[idx[0]] < lam[idx[2]]) { int tt = idx[0]; idx[0] = idx[2]; idx[2] = tt; }
    if (lam[idx[1]] < lam[idx[2]]) { int tt = idx[1]; idx[1] = idx[2]; idx[2] = tt; }
    double Vs[3][3];
    double sv[3];
#pragma unroll
    for (int i = 0; i < 3; ++i) {
        double l = lam[idx[i]];
        sv[i] = sqrt(l > 0.0 ? l : 0.0);
        for (int r = 0; r < 3; ++r) Vs[r][i] = V[r][idx[i]];
    }

    double U[3][3];
#pragma unroll
    for (int i = 0; i < 3; ++i) {
        double kx = K[0][0] * Vs[0][i] + K[0][1] * Vs[1][i] + K[0][2] * Vs[2][i];
        double ky = K[1][0] * Vs[0][i] + K[1][1] * Vs[1][i] + K[1][2] * Vs[2][i];
        double kz = K[2][0] * Vs[0][i] + K[2][1] * Vs[1][i] + K[2][2] * Vs[2][i];
        double inv = (sv[i] > 1e-12 * sv[0] && sv[i] > 0.0) ? 1.0 / sv[i] : 0.0;
        U[0][i] = kx * inv; U[1][i] = ky * inv; U[2][i] = kz * inv;
    }
    if (sv[2] <= 1e-12 * sv[0] || sv[0] == 0.0) {
        U[0][2] = U[1][0] * U[2][1] - U[2][0] * U[1][1];
        U[1][2] = U[2][0] * U[0][1] - U[0][0] * U[2][1];
        U[2][2] = U[0][0] * U[1][1] - U[1][0] * U[0][1];
    }

    double detK = K[0][0] * (K[1][1] * K[2][2] - K[1][2] * K[2][1])
                - K[0][1] * (K[1][0] * K[2][2] - K[1][2] * K[2][0])
                + K[0][2] * (K[1][0] * K[2][1] - K[1][1] * K[2][0]);
    double d = (detK >= 0.0) ? 1.0 : -1.0;
    double scale = (sv[0] + sv[1] + d * sv[2]) / varp;

    float A[9];
#pragma unroll
    for (int a = 0; a < 3; ++a)
#pragma unroll
        for (int b = 0; b < 3; ++b) {
            double r = Vs[a][0] * U[b][0] + Vs[a][1] * U[b][1] + d * Vs[a][2] * U[b][2];
            A[3 * a + b] = (float)(scale * r);
        }
    float tvec[3];
#pragma unroll
    for (int a = 0; a < 3; ++a)
        tvec[a] = (float)(mg[a] - ((double)A[3 * a + 0] * mp[0] + (double)A[3 * a + 1] * mp[1] +
                                   (double)A[3 * a + 2] * mp[2]));

#pragma unroll
    for (int j = 0; j < 9; ++j) ws->At[pair][j] = A[j];
#pragma unroll
    for (int j = 0; j < 3; ++j) ws->At[pair][9 + j] = tvec[j];
}

// ---------------- kernel 3: v2v error on SoA (2p x 4g) ---------
// 1024 blocks = ptile(16)*64 + gtile(64). Proven shape (R0/R1: ~72 us,
// VALUBusy 65%, VGPR 48 / SGPR 112, no spill).
__global__ __launch_bounds__(256, 3) void pair_error_soa(WS* __restrict__ ws) {
    int bx = blockIdx.x;
    int gbase = (bx & 63) * 4;
    int pbase = (bx >> 6) * 2;
    int t = threadIdx.x;

    v2f a03[8], a14[8], a25v[8], t01[8];
    float a6[8], a7[8], a8v[8], t2[8];
#pragma unroll
    for (int gg = 0; gg < 4; ++gg)
#pragma unroll
        for (int pp = 0; pp < 2; ++pp) {
            int i = gg * 2 + pp;
            const float* At = ws->At[(gbase + gg) * P_ + (pbase + pp)];
            a03[i] = v2(At[0], At[3]);
            a14[i] = v2(At[1], At[4]);
            a25v[i] = v2(At[2], At[5]);
            t01[i] = v2(At[9], At[10]);
            a6[i] = At[6]; a7[i] = At[7]; a8v[i] = At[8]; t2[i] = At[11];
        }

    const float4* soa4 = (const float4*)ws->soa;
    const float4* ppx[2]; const float4* ppy[2]; const float4* ppz[2];
    const float4* gpx[4]; const float4* gpy[4]; const float4* gpz[4];
#pragma unroll
    for (int j = 0; j < 2; ++j) {
        const float4* b = soa4 + (size_t)(pbase + j) * SAMPLE_F4;
        ppx[j] = b; ppy[j] = b + QUADS; ppz[j] = b + 2 * QUADS;
    }
#pragma unroll
    for (int j = 0; j < 4; ++j) {
        const float4* c = soa4 + (size_t)(P_ + gbase + j) * SAMPLE_F4;
        gpx[j] = c; gpy[j] = c + QUADS; gpz[j] = c + 2 * QUADS;
    }

    float acc[8];
#pragma unroll
    for (int i = 0; i < 8; ++i) acc[i] = 0.f;

    for (int q = t; q < QUADS; q += 256) {
        float4 PX[2], PY[2], PZ[2];
#pragma unroll
        for (int j = 0; j < 2; ++j) {
            PX[j] = ppx[j][q];
            PY[j] = ppy[j][q];
            PZ[j] = ppz[j][q];
        }
#pragma unroll
        for (int gg = 0; gg < 4; ++gg) {
            float4 GX = gpx[gg][q];
            float4 GY = gpy[gg][q];
            float4 GZ = gpz[gg][q];
            v2f gxy[4] = { v2(GX.x, GY.x), v2(GX.y, GY.y), v2(GX.z, GY.z), v2(GX.w, GY.w) };
            float gz[4] = { GZ.x, GZ.y, GZ.z, GZ.w };
#pragma unroll
            for (int pp = 0; pp < 2; ++pp) {
                int i = gg * 2 + pp;
                float x[4] = { PX[pp].x, PX[pp].y, PX[pp].z, PX[pp].w };
                float y[4] = { PY[pp].x, PY[pp].y, PY[pp].z, PY[pp].w };
                float z[4] = { PZ[pp].x, PZ[pp].y, PZ[pp].z, PZ[pp].w };
                float s = 0.f;
#pragma unroll
                for (int k = 0; k < 4; ++k) {
                    v2f dd = vfma(a03[i], vsplat(x[k]),
                             vfma(a14[i], vsplat(y[k]),
                             vfma(a25v[i], vsplat(z[k]), t01[i])));
                    dd = dd - gxy[k];
                    float dz = fmaf(a6[i], x[k], fmaf(a7[i], y[k], fmaf(a8v[i], z[k], t2[i]))) - gz[k];
                    v2f m = dd * dd;
                    s += __builtin_amdgcn_sqrtf(fmaf(dz, dz, m.x + m.y));
                }
                acc[i] += s;
            }
        }
    }

#pragma unroll
    for (int i = 0; i < 8; ++i) {
        float v = acc[i];
        v += __shfl_xor(v, 1);  v += __shfl_xor(v, 2);
        v += __shfl_xor(v, 4);  v += __shfl_xor(v, 8);
        v += __shfl_xor(v, 16); v += __shfl_xor(v, 32);
        acc[i] = v;
    }
    __shared__ float part[4][8];
    int lane = t & 63, wave = t >> 6;
    if (lane == 0) {
#pragma unroll
        for (int i = 0; i < 8; ++i) part[wave][i] = acc[i];
    }
    __syncthreads();
    if (t < 8) {
        float s = part[0][t] + part[1][t] + part[2][t] + part[3][t];
        int gg = t >> 1, pp = t & 1;
        ws->pair_err[(gbase + gg) * P_ + (pbase + pp)] = s / (float)M_;
    }
}

// ---------------- kernel 4: argmin over gallery + write outputs ----------------
__global__ void argmin_out(const WS* __restrict__ ws, float* __restrict__ out) {
    __shared__ float be[8][32];
    __shared__ int   bg[8][32];
    int t = threadIdx.x;
    int p = t & 31, slice = t >> 5;
    float best = 3.4e38f;
    int bi = G_;
    for (int g = slice; g < G_; g += 8) {
        float e = ws->pair_err[g * P_ + p];
        if (e < best) { best = e; bi = g; }
    }
    be[slice][p] = best;
    bg[slice][p] = bi;
    __syncthreads();
    if (t < P_) {
        float b0 = be[0][t];
        int   i0 = bg[0][t];
        for (int s = 1; s < 8; ++s) {
            float e = be[s][t];
            int   i = bg[s][t];
            if (e < b0 || (e == b0 && i < i0)) { b0 = e; i0 = i; }
        }
        out[t] = (float)i0;
        out[P_ + t] = b0;
    }
}

// ================= fallback path (original AoS kernels) =================
__global__ __launch_bounds__(256, 2) void crosscov_p(const float* __restrict__ pred,
                                                     const float* __restrict__ gt,
                                                     WS* __restrict__ ws) {
    int bx = blockIdx.x;
    int t = threadIdx.x;

    if (bx >= NB_CC) {
        int b = bx - NB_CC;
        bool isP = (b < P_);
        const float* base = isP ? pred + (size_t)b * (M_ * 3)
                                : gt + (size_t)(b - P_) * (M_ * 3);
        double sx = 0, sy = 0, sz = 0, sq = 0;
        for (int q = t; q < QUADS; q += 256) {
            const float4* p4 = (const float4*)(base + 12 * (size_t)q);
            float4 a = p4[0], c = p4[1], d = p4[2];
            sx += (double)a.x + (double)a.w + (double)c.z + (double)d.y;
            sy += (double)a.y + (double)c.x + (double)c.w + (double)d.z;
            sz += (double)a.z + (double)c.y + (double)d.x + (double)d.w;
            if (isP) {
                sq += (double)a.x * a.x + (double)a.y * a.y + (double)a.z * a.z +
                      (double)a.w * a.w + (double)c.x * c.x + (double)c.y * c.y +
                      (double)c.z * c.z + (double)c.w * c.w + (double)d.x * d.x +
                      (double)d.y * d.y + (double)d.z * d.z + (double)d.w * d.w;
            }
        }
        __shared__ double smem[4];
        double rx = block_reduce(sx, smem);
        double ry = block_reduce(sy, smem);
        double rz = block_reduce(sz, smem);
        double rq = block_reduce(sq, smem);
        if (t == 0) {
            double mx = rx / M_, my = ry / M_, mz = rz / M_;
            if (isP) {
                ws->mu_p[b][0] = (float)mx;
                ws->mu_p[b][1] = (float)my;
                ws->mu_p[b][2] = (float)mz;
                ws->var_p[b] = (float)(rq - (mx * mx + my * my + mz * mz) * (double)M_);
            } else {
                ws->mu_g[b - P_][0] = (float)mx;
                ws->mu_g[b - P_][1] = (float)my;
                ws->mu_g[b - P_][2] = (float)mz;
            }
        }
        return;
    }

    int gbase = (bx & 63) * 4;
    int pbase = (bx >> 6) * 4;
    const float* pb[4];
    const float* gb[4];
#pragma unroll
    for (int j = 0; j < 4; ++j) {
        pb[j] = pred + (size_t)(pbase + j) * (M_ * 3);
        gb[j] = gt + (size_t)(gbase + j) * (M_ * 3);
    }

    v2f a01[16], a34[16], a67[16], a25[16];
    float a8[16];
#pragma unroll
    for (int i = 0; i < 16; ++i) {
        a01[i] = vsplat(0.f); a34[i] = vsplat(0.f);
        a67[i] = vsplat(0.f); a25[i] = vsplat(0.f);
        a8[i] = 0.f;
    }

    for (int q = t; q < QUADS; q += 256) {
        float4 P[4][3];
#pragma unroll
        for (int j = 0; j < 4; ++j) {
            const float4* p4 = (const float4*)(pb[j] + 12 * (size_t)q);
            P[j][0] = p4[0]; P[j][1] = p4[1]; P[j][2] = p4[2];
        }
#pragma unroll
        for (int gg = 0; gg < 4; ++gg) {
            const float4* g4 = (const float4*)(gb[gg] + 12 * (size_t)q);
            float4 Ga = g4[0], Gc = g4[1], Gd = g4[2];
            v2f gxy0 = v2(Ga.x, Ga.y), gxy1 = v2(Ga.w, Gc.x);
            v2f gxy2 = v2(Gc.z, Gc.w), gxy3 = v2(Gd.y, Gd.z);
            float gz0 = Ga.z, gz1 = Gc.y, gz2 = Gd.x, gz3 = Gd.w;
#pragma unroll
            for (int pp = 0; pp < 4; ++pp) {
                int i = gg * 4 + pp;
                float4 Pa = P[pp][0], Pc = P[pp][1], Pd = P[pp][2];
                CC_VERT(i, Pa.x, Pa.y, Pa.z, gxy0, gz0)
                CC_VERT(i, Pa.w, Pc.x, Pc.y, gxy1, gz1)
                CC_VERT(i, Pc.z, Pc.w, Pd.x, gxy2, gz2)
                CC_VERT(i, Pd.y, Pd.z, Pd.w, gxy3, gz3)
            }
        }
    }

    float K[16][9];
#pragma unroll
    for (int i = 0; i < 16; ++i) {
        K[i][0] = a01[i].x; K[i][1] = a01[i].y; K[i][2] = a25[i].x;
        K[i][3] = a34[i].x; K[i][4] = a34[i].y; K[i][5] = a25[i].y;
        K[i][6] = a67[i].x; K[i][7] = a67[i].y; K[i][8] = a8[i];
    }
#pragma unroll
    for (int i = 0; i < 16; ++i)
#pragma unroll
        for (int j = 0; j < 9; ++j) {
            float v = K[i][j];
            v += __shfl_xor(v, 1);  v += __shfl_xor(v, 2);
            v += __shfl_xor(v, 4);  v += __shfl_xor(v, 8);
            v += __shfl_xor(v, 16); v += __shfl_xor(v, 32);
            K[i][j] = v;
        }
    __shared__ float part[4][144];
    int lane = t & 63, wave = t >> 6;
    if (lane == 0) {
#pragma unroll
        for (int i = 0; i < 16; ++i)
#pragma unroll
            for (int j = 0; j < 9; ++j) part[wave][i * 9 + j] = K[i][j];
    }
    __syncthreads();
    if (t < 144) {
        float s = part[0][t] + part[1][t] + part[2][t] + part[3][t];
        int idx = t / 9, j = t % 9;
        int gg = idx >> 2, pp = idx & 3;
        ws->Kmat[(gbase + gg) * P_ + (pbase + pp)][j] = s;
    }
}

__global__ __launch_bounds__(256, 3) void pair_error_p(const float* __restrict__ pred,
                                                       const float* __restrict__ gt,
                                                       WS* __restrict__ ws) {
    int bx = blockIdx.x;
    int gbase = (bx & 63) * 4;
    int pbase = (bx >> 6) * 2;
    int t = threadIdx.x;

    v2f a03[8], a14[8], a25v[8], t01[8];
    float a6[8], a7[8], a8v[8], t2[8];
#pragma unroll
    for (int gg = 0; gg < 4; ++gg)
#pragma unroll
        for (int pp = 0; pp < 2; ++pp) {
            int i = gg * 2 + pp;
            const float* At = ws->At[(gbase + gg) * P_ + (pbase + pp)];
            a03[i] = v2(At[0], At[3]);
            a14[i] = v2(At[1], At[4]);
            a25v[i] = v2(At[2], At[5]);
            t01[i] = v2(At[9], At[10]);
            a6[i] = At[6]; a7[i] = At[7]; a8v[i] = At[8]; t2[i] = At[11];
        }

    const float* pb0 = pred + (size_t)pbase * (M_ * 3);
    const float* pb1 = pred + (size_t)(pbase + 1) * (M_ * 3);
    const float* gb[4];
#pragma unroll
    for (int j = 0; j < 4; ++j) gb[j] = gt + (size_t)(gbase + j) * (M_ * 3);

    float acc[8];
#pragma unroll
    for (int i = 0; i < 8; ++i) acc[i] = 0.f;

    for (int q = t; q < QUADS; q += 256) {
        float4 P[2][3];
        {
            const float4* p4 = (const float4*)(pb0 + 12 * (size_t)q);
            P[0][0] = p4[0]; P[0][1] = p4[1]; P[0][2] = p4[2];
            p4 = (const float4*)(pb1 + 12 * (size_t)q);
            P[1][0] = p4[0]; P[1][1] = p4[1]; P[1][2] = p4[2];
        }
#pragma unroll
        for (int gg = 0; gg < 4; ++gg) {
            const float4* g4 = (const float4*)(gb[gg] + 12 * (size_t)q);
            float4 Ga = g4[0], Gc = g4[1], Gd = g4[2];
            v2f gxy[4] = { v2(Ga.x, Ga.y), v2(Ga.w, Gc.x), v2(Gc.z, Gc.w), v2(Gd.y, Gd.z) };
            float gz[4] = { Ga.z, Gc.y, Gd.x, Gd.w };
#pragma unroll
            for (int pp = 0; pp < 2; ++pp) {
                int i = gg * 2 + pp;
                float4 Pa = P[pp][0], Pc = P[pp][1], Pd = P[pp][2];
                float x[4] = { Pa.x, Pa.w, Pc.z, Pd.y };
                float y[4] = { Pa.y, Pc.x, Pc.w, Pd.z };
                float z[4] = { Pa.z, Pc.y, Pd.x, Pd.w };
                float s = 0.f;
#pragma unroll
                for (int k = 0; k < 4; ++k) {
                    v2f dd = vfma(a03[i], vsplat(x[k]),
                             vfma(a14[i], vsplat(y[k]),
                             vfma(a25v[i], vsplat(z[k]), t01[i])));
                    dd = dd - gxy[k];
                    float dz = fmaf(a6[i], x[k], fmaf(a7[i], y[k], fmaf(a8v[i], z[k], t2[i]))) - gz[k];
                    v2f m = dd * dd;
                    s += __builtin_amdgcn_sqrtf(fmaf(dz, dz, m.x + m.y));
                }
                acc[i] += s;
            }
        }
    }

#pragma unroll
    for (int i = 0; i < 8; ++i) {
        float v = acc[i];
        v += __shfl_xor(v, 1);  v += __shfl_xor(v, 2);
        v += __shfl_xor(v, 4);  v += __shfl_xor(v, 8);
        v += __shfl_xor(v, 16); v += __shfl_xor(v, 32);
        acc[i] = v;
    }
    __shared__ float part[4][8];
    int lane = t & 63, wave = t >> 6;
    if (lane == 0) {
#pragma unroll
        for (int i = 0; i < 8; ++i) part[wave][i] = acc[i];
    }
    __syncthreads();
    if (t < 8) {
        float s = part[0][t] + part[1][t] + part[2][t] + part[3][t];
        int gg = t >> 1, pp = t & 1;
        ws->pair_err[(gbase + gg) * P_ + (pbase + pp)] = s / (float)M_;
    }
}

extern "C" void kernel_launch(void* const* d_in, const int* in_sizes, int n_in,
                              void* d_out, int out_size, void* d_ws, size_t ws_size,
                              hipStream_t stream) {
    const float* pred = (const float*)d_in[0];   // (32, 2, 6890, 3)
    const float* gt   = (const float*)d_in[1];   // (256, 2, 6890, 3)
    float* out = (float*)d_out;                  // 64 floats: mapping(32) | min_error(32)
    WS* ws = (WS*)d_ws;

    if (ws_size >= sizeof(WS)) {
        // SoA path: repack (+stats) once, then fully-coalesced heavy kernels.
        hipMemsetAsync(d_ws, 0, sizeof(double) * SAMPLES * 4, stream);
        repack_stats<<<dim3(SAMPLES * NCHUNK), dim3(256), 0, stream>>>(pred, gt, ws);
        crosscov_soa<<<dim3(8 * 64), dim3(256), 0, stream>>>(ws);
        pair_svd<<<dim3(NPAIR / 64), dim3(64), 0, stream>>>(ws, 1);
        pair_error_soa<<<dim3(16 * 64), dim3(256), 0, stream>>>(ws);
        argmin_out<<<dim3(1), dim3(256), 0, stream>>>(ws, out);
    } else {
        // fallback: original AoS path (workspace too small for SoA copy)
        crosscov_p<<<dim3(NB_CC + P_ + G_), dim3(256), 0, stream>>>(pred, gt, ws);
        pair_svd<<<dim3(NPAIR / 64), dim3(64), 0, stream>>>(ws, 0);
        pair_error_p<<<dim3(16 * 64), dim3(256), 0, stream>>>(pred, gt, ws);
        argmin_out<<<dim3(1), dim3(256), 0, stream>>>(ws, out);
    }
}

// Round 6
// 223.454 us; speedup vs baseline: 2.4784x; 1.1819x over previous
//
#include <hip/hip_runtime.h>
#include <math.h>

#define P_ 32
#define G_ 256
#define NV 6890
#define M_ (2 * NV)          // 13780 joint points per sample
#define QUADS (M_ / 4)       // 3445 vertex-quads (exact)
#define NPAIR (P_ * G_)      // 8192
#define NB_WS 256            // wave-split crosscov blocks; stats appended after
#define CHUNK_Q 128          // quads staged to LDS per chunk
#define NCHUNKS ((QUADS + CHUNK_Q - 1) / CHUNK_Q)   // 27 (tail = 117)

typedef float v2f __attribute__((ext_vector_type(2)));
__device__ inline v2f v2(float a, float b) { v2f r; r.x = a; r.y = b; return r; }
__device__ inline v2f vsplat(float a) { v2f r; r.x = a; r.y = a; return r; }
__device__ inline v2f vfma(v2f a, v2f b, v2f c) { return __builtin_elementwise_fma(a, b, c); }

// ---------------- workspace layout (small again: ~0.75 MB) ----------------
struct WS {
    float mu_p[P_][3];
    float var_p[P_];
    float mu_g[G_][3];
    float At[NPAIR][12];     // A = scale*R (9) then t (3); pair = g*32 + p
    float Kmat[NPAIR][9];    // cross-covariance (pre mean-subtraction)
    float pair_err[NPAIR];   // mean v2v error per pair
};

// ---------------- block reduction (valid on thread 0; supports 512 thr) ----
__device__ inline double block_reduce(double v, double* smem) {
#pragma unroll
    for (int off = 32; off > 0; off >>= 1) v += __shfl_down(v, off, 64);
    int wid  = threadIdx.x >> 6;
    int lane = threadIdx.x & 63;
    __syncthreads();
    if (lane == 0) smem[wid] = v;
    __syncthreads();
    double r = 0.0;
    if (threadIdx.x == 0) {
        int nw = blockDim.x >> 6;
        for (int w = 0; w < nw; ++w) r += smem[w];
    }
    return r;
}

// ---------------- kernel 1: wave-split crosscov (8p x 4g per block) -------
// Lesson history: thread-tiled variants are latency-bound (VALU 26-28% at
// 2-4 waves/SIMD regardless of traffic: AoS4p=72us, SoA2p=84, SoA4p=92).
// This kernel breaks VGPR<->waves deadlock: wave w owns p=pbase+w (only 4
// pairs -> 36 acc floats/thread); the 4 shared g-streams are LDS-staged per
// 128-quad chunk, deinterleaved to xyz planes for dense conflict-free
// ds_read_b128. ~100 VGPR -> 4 waves/SIMD (16 waves/CU).
// Blocks 0..255: bx = ptile*64 + gtile; XCD = gtile%8 (g L2-locality).
// Blocks 256..543: per-sample stats (0..31 pred mu/var, 32..287 gt mu).
__global__ __launch_bounds__(512) void crosscov_ws(const float* __restrict__ pred,
                                                   const float* __restrict__ gt,
                                                   WS* __restrict__ ws) {
    int bx = blockIdx.x;
    int t = threadIdx.x;

    if (bx >= NB_WS) {
        // ---- stats path (512-thread grid-stride) ----
        int b = bx - NB_WS;
        bool isP = (b < P_);
        const float* base = isP ? pred + (size_t)b * (M_ * 3)
                                : gt + (size_t)(b - P_) * (M_ * 3);
        double sx = 0, sy = 0, sz = 0, sq = 0;
        for (int q = t; q < QUADS; q += 512) {
            const float4* p4 = (const float4*)(base + 12 * (size_t)q);
            float4 a = p4[0], c = p4[1], d = p4[2];
            sx += (double)a.x + (double)a.w + (double)c.z + (double)d.y;
            sy += (double)a.y + (double)c.x + (double)c.w + (double)d.z;
            sz += (double)a.z + (double)c.y + (double)d.x + (double)d.w;
            if (isP) {
                sq += (double)a.x * a.x + (double)a.y * a.y + (double)a.z * a.z +
                      (double)a.w * a.w + (double)c.x * c.x + (double)c.y * c.y +
                      (double)c.z * c.z + (double)c.w * c.w + (double)d.x * d.x +
                      (double)d.y * d.y + (double)d.z * d.z + (double)d.w * d.w;
            }
        }
        __shared__ double smem[8];
        double rx = block_reduce(sx, smem);
        double ry = block_reduce(sy, smem);
        double rz = block_reduce(sz, smem);
        double rq = block_reduce(sq, smem);
        if (t == 0) {
            double mx = rx / M_, my = ry / M_, mz = rz / M_;
            if (isP) {
                ws->mu_p[b][0] = (float)mx;
                ws->mu_p[b][1] = (float)my;
                ws->mu_p[b][2] = (float)mz;
                ws->var_p[b] = (float)(rq - (mx * mx + my * my + mz * mz) * (double)M_);
            } else {
                ws->mu_g[b - P_][0] = (float)mx;
                ws->mu_g[b - P_][1] = (float)my;
                ws->mu_g[b - P_][2] = (float)mz;
            }
        }
        return;
    }

    // ---- wave-split crosscov path ----
    int gbase = (bx & 63) * 4;
    int pbase = (bx >> 6) * 8;     // 4 ptiles of 8
    int wave = t >> 6;
    int lane = t & 63;
    int p = pbase + wave;          // this wave's pred sample

    const float* pb = pred + (size_t)p * (M_ * 3);
    // staging assignment: thread t stages stream ss, f4 slots si, si+128, si+256
    int ss = t >> 7;               // 0..3
    int si = t & 127;
    const float4* gsrc = (const float4*)(gt + (size_t)(gbase + ss) * (M_ * 3));

    // LDS: xyz planes per g-stream, CHUNK_Q*4 points each => 24 KB
    __shared__ __align__(16) float glds[3][4][CHUNK_Q * 4];

    v2f a01[4], a34[4], a67[4], a25[4];
    float a8[4];
#pragma unroll
    for (int i = 0; i < 4; ++i) {
        a01[i] = vsplat(0.f); a34[i] = vsplat(0.f);
        a67[i] = vsplat(0.f); a25[i] = vsplat(0.f);
        a8[i] = 0.f;
    }

    for (int c = 0; c < NCHUNKS; ++c) {
        int qb = c * CHUNK_Q;
        int nq = QUADS - qb; if (nq > CHUNK_Q) nq = CHUNK_Q;
        __syncthreads();   // previous chunk's LDS reads done
        // stage + deinterleave: 3 f4 per thread, scalar writes to planes
#pragma unroll
        for (int r = 0; r < 3; ++r) {
            int fi = si + r * 128;                 // f4 index in stream-chunk
            if (fi < 3 * nq) {
                float4 v = gsrc[(size_t)qb * 3 + fi];
                float vv[4] = { v.x, v.y, v.z, v.w };
#pragma unroll
                for (int j = 0; j < 4; ++j) {
                    int f = 4 * fi + j;            // float index in chunk
                    glds[f % 3][ss][f / 3] = vv[j];
                }
            }
        }
        __syncthreads();   // chunk staged
#pragma unroll
        for (int sub = 0; sub < 2; ++sub) {
            int qq = lane + sub * 64;
            if (qq < nq) {
                const float4* p4 = (const float4*)(pb + 12 * (size_t)(qb + qq));
                float4 Pa = p4[0], Pc = p4[1], Pd = p4[2];
                float x[4] = { Pa.x, Pa.w, Pc.z, Pd.y };
                float y[4] = { Pa.y, Pc.x, Pc.w, Pd.z };
                float z[4] = { Pa.z, Pc.y, Pd.x, Pd.w };
#pragma unroll
                for (int gg = 0; gg < 4; ++gg) {
                    float4 GX = *(const float4*)&glds[0][gg][4 * qq];
                    float4 GY = *(const float4*)&glds[1][gg][4 * qq];
                    float4 GZ = *(const float4*)&glds[2][gg][4 * qq];
                    float gxv[4] = { GX.x, GX.y, GX.z, GX.w };
                    float gyv[4] = { GY.x, GY.y, GY.z, GY.w };
                    float gzv[4] = { GZ.x, GZ.y, GZ.z, GZ.w };
#pragma unroll
                    for (int k = 0; k < 4; ++k) {
                        v2f gxy = v2(gxv[k], gyv[k]);
                        a01[gg] = vfma(vsplat(x[k]), gxy, a01[gg]);
                        a34[gg] = vfma(vsplat(y[k]), gxy, a34[gg]);
                        a67[gg] = vfma(vsplat(z[k]), gxy, a67[gg]);
                        a25[gg] = vfma(v2(x[k], y[k]), vsplat(gzv[k]), a25[gg]);
                        a8[gg]  = fmaf(z[k], gzv[k], a8[gg]);
                    }
                }
            }
        }
    }

    // per-wave butterfly; pair (p, gbase+gg) owned by exactly this wave
    float K[4][9];
#pragma unroll
    for (int i = 0; i < 4; ++i) {
        K[i][0] = a01[i].x; K[i][1] = a01[i].y; K[i][2] = a25[i].x;
        K[i][3] = a34[i].x; K[i][4] = a34[i].y; K[i][5] = a25[i].y;
        K[i][6] = a67[i].x; K[i][7] = a67[i].y; K[i][8] = a8[i];
    }
#pragma unroll
    for (int i = 0; i < 4; ++i)
#pragma unroll
        for (int j = 0; j < 9; ++j) {
            float v = K[i][j];
            v += __shfl_xor(v, 1);  v += __shfl_xor(v, 2);
            v += __shfl_xor(v, 4);  v += __shfl_xor(v, 8);
            v += __shfl_xor(v, 16); v += __shfl_xor(v, 32);
            K[i][j] = v;
        }
    if (lane == 0) {
#pragma unroll
        for (int gg = 0; gg < 4; ++gg)
#pragma unroll
            for (int j = 0; j < 9; ++j)
                ws->Kmat[(gbase + gg) * P_ + p][j] = K[gg][j];
    }
}

// ---------------- kernel 2: per-pair SVD -> A = scale*R, t ----------------
__global__ void pair_svd(WS* __restrict__ ws) {
    int pair = blockIdx.x * blockDim.x + threadIdx.x;
    if (pair >= NPAIR) return;
    int p = pair & 31;
    int g = pair >> 5;

    double mp[3] = { ws->mu_p[p][0], ws->mu_p[p][1], ws->mu_p[p][2] };
    double mg[3] = { ws->mu_g[g][0], ws->mu_g[g][1], ws->mu_g[g][2] };
    double varp = (double)ws->var_p[p];

    double K[3][3];
#pragma unroll
    for (int a = 0; a < 3; ++a)
#pragma unroll
        for (int b = 0; b < 3; ++b)
            K[a][b] = (double)ws->Kmat[pair][3 * a + b] - (double)M_ * mp[a] * mg[b];

    // S = K^T K (symmetric PSD)
    double S[3][3];
#pragma unroll
    for (int a = 0; a < 3; ++a)
#pragma unroll
        for (int b = 0; b < 3; ++b) {
            double acc = 0.0;
#pragma unroll
            for (int c = 0; c < 3; ++c) acc += K[c][a] * K[c][b];
            S[a][b] = acc;
        }

    // Jacobi eigendecomposition S = V Lambda V^T
    double V[3][3] = { {1, 0, 0}, {0, 1, 0}, {0, 0, 1} };
    double tr = S[0][0] + S[1][1] + S[2][2];
    double tol = 1e-30 * tr * tr + 1e-300;
    const int PP[3] = {0, 0, 1};
    const int QQ[3] = {1, 2, 2};
    for (int sweep = 0; sweep < 30; ++sweep) {
        double off = S[0][1] * S[0][1] + S[0][2] * S[0][2] + S[1][2] * S[1][2];
        if (off <= tol) break;
        for (int r3 = 0; r3 < 3; ++r3) {
            int pq = PP[r3], qq = QQ[r3];
            double apq = S[pq][qq];
            if (apq == 0.0) continue;
            double theta = (S[qq][qq] - S[pq][pq]) / (2.0 * apq);
            double tt = copysign(1.0, theta) / (fabs(theta) + sqrt(theta * theta + 1.0));
            double c = 1.0 / sqrt(tt * tt + 1.0);
            double sj = tt * c;
            for (int r = 0; r < 3; ++r) {
                double srp = S[r][pq], srq = S[r][qq];
                S[r][pq] = c * srp - sj * srq;
                S[r][qq] = sj * srp + c * srq;
            }
            for (int cc = 0; cc < 3; ++cc) {
                double spr = S[pq][cc], sqr = S[qq][cc];
                S[pq][cc] = c * spr - sj * sqr;
                S[qq][cc] = sj * spr + c * sqr;
            }
            for (int r = 0; r < 3; ++r) {
                double vrp = V[r][pq], vrq = V[r][qq];
                V[r][pq] = c * vrp - sj * vrq;
                V[r][qq] = sj * vrp + c * vrq;
            }
        }
    }

    double lam[3] = { S[0][0], S[1][1], S[2][2] };
    int idx[3] = { 0, 1, 2 };
    if (lam[idx[0]] < lam[idx[1]]) { int tt = idx[0]; idx[0] = idx[1]; idx[1] = tt; }
    if (lam[idx[0]] < lam[idx[2]]) { int tt = idx[0]; idx[0] = idx[2]; idx[2] = tt; }
    if (lam[idx[1]] < lam[idx[2]]) { int tt = idx[1]; idx[1] = idx[2]; idx[2] = tt; }
    double Vs[3][3];
    double sv[3];
#pragma unroll
    for (int i = 0; i < 3; ++i) {
        double l = lam[idx[i]];
        sv[i] = sqrt(l > 0.0 ? l : 0.0);
        for (int r = 0; r < 3; ++r) Vs[r][i] = V[r][idx[i]];
    }

    double U[3][3];
#pragma unroll
    for (int i = 0; i < 3; ++i) {
        double kx = K[0][0] * Vs[0][i] + K[0][1] * Vs[1][i] + K[0][2] * Vs[2][i];
        double ky = K[1][0] * Vs[0][i] + K[1][1] * Vs[1][i] + K[1][2] * Vs[2][i];
        double kz = K[2][0] * Vs[0][i] + K[2][1] * Vs[1][i] + K[2][2] * Vs[2][i];
        double inv = (sv[i] > 1e-12 * sv[0] && sv[i] > 0.0) ? 1.0 / sv[i] : 0.0;
        U[0][i] = kx * inv; U[1][i] = ky * inv; U[2][i] = kz * inv;
    }
    if (sv[2] <= 1e-12 * sv[0] || sv[0] == 0.0) {
        U[0][2] = U[1][0] * U[2][1] - U[2][0] * U[1][1];
        U[1][2] = U[2][0] * U[0][1] - U[0][0] * U[2][1];
        U[2][2] = U[0][0] * U[1][1] - U[1][0] * U[0][1];
    }

    double detK = K[0][0] * (K[1][1] * K[2][2] - K[1][2] * K[2][1])
                - K[0][1] * (K[1][0] * K[2][2] - K[1][2] * K[2][0])
                + K[0][2] * (K[1][0] * K[2][1] - K[1][1] * K[2][0]);
    double d = (detK >= 0.0) ? 1.0 : -1.0;
    double scale = (sv[0] + sv[1] + d * sv[2]) / varp;

    float A[9];
#pragma unroll
    for (int a = 0; a < 3; ++a)
#pragma unroll
        for (int b = 0; b < 3; ++b) {
            double r = Vs[a][0] * U[b][0] + Vs[a][1] * U[b][1] + d * Vs[a][2] * U[b][2];
            A[3 * a + b] = (float)(scale * r);
        }
    float tvec[3];
#pragma unroll
    for (int a = 0; a < 3; ++a)
        tvec[a] = (float)(mg[a] - ((double)A[3 * a + 0] * mp[0] + (double)A[3 * a + 1] * mp[1] +
                                   (double)A[3 * a + 2] * mp[2]));

#pragma unroll
    for (int j = 0; j < 9; ++j) ws->At[pair][j] = A[j];
#pragma unroll
    for (int j = 0; j < 3; ++j) ws->At[pair][9 + j] = tvec[j];
}

// ---------------- kernel 3: packed v2v error (2p x 4g, AoS) ----------------
// Proven R0 shape: 1024 blocks, VGPR 48 / SGPR 112, VALUBusy ~65%, ~72 us.
__global__ __launch_bounds__(256, 3) void pair_error_p(const float* __restrict__ pred,
                                                       const float* __restrict__ gt,
                                                       WS* __restrict__ ws) {
    int bx = blockIdx.x;
    int gbase = (bx & 63) * 4;
    int pbase = (bx >> 6) * 2;
    int t = threadIdx.x;

    v2f a03[8], a14[8], a25v[8], t01[8];
    float a6[8], a7[8], a8v[8], t2[8];
#pragma unroll
    for (int gg = 0; gg < 4; ++gg)
#pragma unroll
        for (int pp = 0; pp < 2; ++pp) {
            int i = gg * 2 + pp;
            const float* At = ws->At[(gbase + gg) * P_ + (pbase + pp)];
            a03[i] = v2(At[0], At[3]);
            a14[i] = v2(At[1], At[4]);
            a25v[i] = v2(At[2], At[5]);
            t01[i] = v2(At[9], At[10]);
            a6[i] = At[6]; a7[i] = At[7]; a8v[i] = At[8]; t2[i] = At[11];
        }

    const float* pb0 = pred + (size_t)pbase * (M_ * 3);
    const float* pb1 = pred + (size_t)(pbase + 1) * (M_ * 3);
    const float* gb[4];
#pragma unroll
    for (int j = 0; j < 4; ++j) gb[j] = gt + (size_t)(gbase + j) * (M_ * 3);

    float acc[8];
#pragma unroll
    for (int i = 0; i < 8; ++i) acc[i] = 0.f;

    for (int q = t; q < QUADS; q += 256) {
        float4 P[2][3];
        {
            const float4* p4 = (const float4*)(pb0 + 12 * (size_t)q);
            P[0][0] = p4[0]; P[0][1] = p4[1]; P[0][2] = p4[2];
            p4 = (const float4*)(pb1 + 12 * (size_t)q);
            P[1][0] = p4[0]; P[1][1] = p4[1]; P[1][2] = p4[2];
        }
#pragma unroll
        for (int gg = 0; gg < 4; ++gg) {
            const float4* g4 = (const float4*)(gb[gg] + 12 * (size_t)q);
            float4 Ga = g4[0], Gc = g4[1], Gd = g4[2];
            v2f gxy[4] = { v2(Ga.x, Ga.y), v2(Ga.w, Gc.x), v2(Gc.z, Gc.w), v2(Gd.y, Gd.z) };
            float gz[4] = { Ga.z, Gc.y, Gd.x, Gd.w };
#pragma unroll
            for (int pp = 0; pp < 2; ++pp) {
                int i = gg * 2 + pp;
                float4 Pa = P[pp][0], Pc = P[pp][1], Pd = P[pp][2];
                float x[4] = { Pa.x, Pa.w, Pc.z, Pd.y };
                float y[4] = { Pa.y, Pc.x, Pc.w, Pd.z };
                float z[4] = { Pa.z, Pc.y, Pd.x, Pd.w };
                float s = 0.f;
#pragma unroll
                for (int k = 0; k < 4; ++k) {
                    v2f dd = vfma(a03[i], vsplat(x[k]),
                             vfma(a14[i], vsplat(y[k]),
                             vfma(a25v[i], vsplat(z[k]), t01[i])));
                    dd = dd - gxy[k];
                    float dz = fmaf(a6[i], x[k], fmaf(a7[i], y[k], fmaf(a8v[i], z[k], t2[i]))) - gz[k];
                    v2f m = dd * dd;
                    s += __builtin_amdgcn_sqrtf(fmaf(dz, dz, m.x + m.y));
                }
                acc[i] += s;
            }
        }
    }

#pragma unroll
    for (int i = 0; i < 8; ++i) {
        float v = acc[i];
        v += __shfl_xor(v, 1);  v += __shfl_xor(v, 2);
        v += __shfl_xor(v, 4);  v += __shfl_xor(v, 8);
        v += __shfl_xor(v, 16); v += __shfl_xor(v, 32);
        acc[i] = v;
    }
    __shared__ float part[4][8];
    int lane = t & 63, wave = t >> 6;
    if (lane == 0) {
#pragma unroll
        for (int i = 0; i < 8; ++i) part[wave][i] = acc[i];
    }
    __syncthreads();
    if (t < 8) {
        float s = part[0][t] + part[1][t] + part[2][t] + part[3][t];
        int gg = t >> 1, pp = t & 1;
        ws->pair_err[(gbase + gg) * P_ + (pbase + pp)] = s / (float)M_;
    }
}

// ---------------- kernel 4: argmin over gallery + write outputs ----------------
__global__ void argmin_out(const WS* __restrict__ ws, float* __restrict__ out) {
    __shared__ float be[8][32];
    __shared__ int   bg[8][32];
    int t = threadIdx.x;
    int p = t & 31, slice = t >> 5;
    float best = 3.4e38f;
    int bi = G_;
    for (int g = slice; g < G_; g += 8) {
        float e = ws->pair_err[g * P_ + p];
        if (e < best) { best = e; bi = g; }
    }
    be[slice][p] = best;
    bg[slice][p] = bi;
    __syncthreads();
    if (t < P_) {
        float b0 = be[0][t];
        int   i0 = bg[0][t];
        for (int s = 1; s < 8; ++s) {
            float e = be[s][t];
            int   i = bg[s][t];
            if (e < b0 || (e == b0 && i < i0)) { b0 = e; i0 = i; }
        }
        out[t] = (float)i0;
        out[P_ + t] = b0;
    }
}

extern "C" void kernel_launch(void* const* d_in, const int* in_sizes, int n_in,
                              void* d_out, int out_size, void* d_ws, size_t ws_size,
                              hipStream_t stream) {
    const float* pred = (const float*)d_in[0];   // (32, 2, 6890, 3)
    const float* gt   = (const float*)d_in[1];   // (256, 2, 6890, 3)
    float* out = (float*)d_out;                  // 64 floats: mapping(32) | min_error(32)
    WS* ws = (WS*)d_ws;                          // ~0.75 MB used

    crosscov_ws<<<dim3(NB_WS + P_ + G_), dim3(512), 0, stream>>>(pred, gt, ws);
    pair_svd<<<dim3(NPAIR / 64), dim3(64), 0, stream>>>(ws);
    pair_error_p<<<dim3(16 * 64), dim3(256), 0, stream>>>(pred, gt, ws);
    argmin_out<<<dim3(1), dim3(256), 0, stream>>>(ws, out);
}

// Round 7
// 216.202 us; speedup vs baseline: 2.5616x; 1.0335x over previous
//
#include <hip/hip_runtime.h>
#include <math.h>

#define P_ 32
#define G_ 256
#define NV 6890
#define M_ (2 * NV)          // 13780 joint points per sample
#define QUADS (M_ / 4)       // 3445 vertex-quads (exact)
#define NPAIR (P_ * G_)      // 8192
#define NB_WS 512            // wave-split crosscov blocks (2-way quad split)
#define CHUNK_Q 128          // quads staged to LDS per chunk
#define NCHUNKS ((QUADS + CHUNK_Q - 1) / CHUNK_Q)   // 27 (tail = 117)
#define HALF_CH 14           // chunks in quad-half 0 (half 1 gets 13)

typedef float v2f __attribute__((ext_vector_type(2)));
__device__ inline v2f v2(float a, float b) { v2f r; r.x = a; r.y = b; return r; }
__device__ inline v2f vsplat(float a) { v2f r; r.x = a; r.y = a; return r; }
__device__ inline v2f vfma(v2f a, v2f b, v2f c) { return __builtin_elementwise_fma(a, b, c); }

// ---------------- workspace layout (~1 MB) ----------------
struct WS {
    float mu_p[P_][3];
    float var_p[P_];
    float mu_g[G_][3];
    float At[NPAIR][12];      // A = scale*R (9) then t (3); pair = g*32 + p
    float Kmat[2][NPAIR][9];  // partial cross-cov per quad-half (summed in svd)
    float pair_err[NPAIR];    // mean v2v error per pair
};

// ---------------- block reduction (valid on thread 0; supports 512 thr) ----
__device__ inline double block_reduce(double v, double* smem) {
#pragma unroll
    for (int off = 32; off > 0; off >>= 1) v += __shfl_down(v, off, 64);
    int wid  = threadIdx.x >> 6;
    int lane = threadIdx.x & 63;
    __syncthreads();
    if (lane == 0) smem[wid] = v;
    __syncthreads();
    double r = 0.0;
    if (threadIdx.x == 0) {
        int nw = blockDim.x >> 6;
        for (int w = 0; w < nw; ++w) r += smem[w];
    }
    return r;
}

// ---------------- kernel 1: wave-split crosscov (8p x 4g x qhalf) --------
// R6 lesson: 256 blocks = 1 block/CU = 2 waves/SIMD -> latency-serialized
// (VALU 29%, occ 25%). Fix: (a) 2-way quad split -> 512 blocks, 2/CU,
// 16 waves/CU; (b) issue-early staging: next chunk's global loads are
// issued into regs before the barrier, latency hides under compute.
// Wave w owns p = pbase+w (4 pairs -> 36 acc floats). g-streams staged to
// LDS deinterleaved xyz planes per 128-quad chunk (24 KB).
// Blocks 0..511: bx = qhalf*256 + ptile*64 + gtile; XCD = gtile%8.
// Blocks 512..799: per-sample stats (0..31 pred mu/var, 32..287 gt mu).
__global__ __launch_bounds__(512) void crosscov_ws(const float* __restrict__ pred,
                                                   const float* __restrict__ gt,
                                                   WS* __restrict__ ws) {
    int bx = blockIdx.x;
    int t = threadIdx.x;

    if (bx >= NB_WS) {
        // ---- stats path (512-thread grid-stride) ----
        int b = bx - NB_WS;
        bool isP = (b < P_);
        const float* base = isP ? pred + (size_t)b * (M_ * 3)
                                : gt + (size_t)(b - P_) * (M_ * 3);
        double sx = 0, sy = 0, sz = 0, sq = 0;
        for (int q = t; q < QUADS; q += 512) {
            const float4* p4 = (const float4*)(base + 12 * (size_t)q);
            float4 a = p4[0], c = p4[1], d = p4[2];
            sx += (double)a.x + (double)a.w + (double)c.z + (double)d.y;
            sy += (double)a.y + (double)c.x + (double)c.w + (double)d.z;
            sz += (double)a.z + (double)c.y + (double)d.x + (double)d.w;
            if (isP) {
                sq += (double)a.x * a.x + (double)a.y * a.y + (double)a.z * a.z +
                      (double)a.w * a.w + (double)c.x * c.x + (double)c.y * c.y +
                      (double)c.z * c.z + (double)c.w * c.w + (double)d.x * d.x +
                      (double)d.y * d.y + (double)d.z * d.z + (double)d.w * d.w;
            }
        }
        __shared__ double smem[8];
        double rx = block_reduce(sx, smem);
        double ry = block_reduce(sy, smem);
        double rz = block_reduce(sz, smem);
        double rq = block_reduce(sq, smem);
        if (t == 0) {
            double mx = rx / M_, my = ry / M_, mz = rz / M_;
            if (isP) {
                ws->mu_p[b][0] = (float)mx;
                ws->mu_p[b][1] = (float)my;
                ws->mu_p[b][2] = (float)mz;
                ws->var_p[b] = (float)(rq - (mx * mx + my * my + mz * mz) * (double)M_);
            } else {
                ws->mu_g[b - P_][0] = (float)mx;
                ws->mu_g[b - P_][1] = (float)my;
                ws->mu_g[b - P_][2] = (float)mz;
            }
        }
        return;
    }

    // ---- wave-split crosscov path ----
    int qhalf = bx >> 8;           // 0 or 1
    int rem = bx & 255;
    int gbase = (rem & 63) * 4;
    int pbase = (rem >> 6) * 8;    // 4 ptiles of 8
    int c0 = qhalf * HALF_CH;
    int c1 = qhalf ? NCHUNKS : HALF_CH;
    int wave = t >> 6;
    int lane = t & 63;
    int p = pbase + wave;          // this wave's pred sample

    const float* pb = pred + (size_t)p * (M_ * 3);
    // staging assignment: thread t stages stream ss, f4 slots si, si+128, si+256
    int ss = t >> 7;               // 0..3
    int si = t & 127;
    const float4* gsrc = (const float4*)(gt + (size_t)(gbase + ss) * (M_ * 3));

    // LDS: xyz planes per g-stream, CHUNK_Q*4 points each => 24 KB
    __shared__ __align__(16) float glds[3][4][CHUNK_Q * 4];

    v2f a01[4], a34[4], a67[4], a25[4];
    float a8[4];
#pragma unroll
    for (int i = 0; i < 4; ++i) {
        a01[i] = vsplat(0.f); a34[i] = vsplat(0.f);
        a67[i] = vsplat(0.f); a25[i] = vsplat(0.f);
        a8[i] = 0.f;
    }

    // prefetch first chunk's staging loads into regs
    float4 stg[3];
    {
        int qb = c0 * CHUNK_Q;
        int nq = QUADS - qb; if (nq > CHUNK_Q) nq = CHUNK_Q;
#pragma unroll
        for (int r = 0; r < 3; ++r) {
            int fi = si + r * 128;
            stg[r] = (fi < 3 * nq) ? gsrc[(size_t)qb * 3 + fi]
                                   : make_float4(0.f, 0.f, 0.f, 0.f);
        }
    }

    for (int c = c0; c < c1; ++c) {
        int qb = c * CHUNK_Q;
        int nq = QUADS - qb; if (nq > CHUNK_Q) nq = CHUNK_Q;
        __syncthreads();   // previous chunk's LDS reads done
        // write staged regs to LDS, deinterleaved to xyz planes
#pragma unroll
        for (int r = 0; r < 3; ++r) {
            int fi = si + r * 128;                 // f4 index in stream-chunk
            if (fi < 3 * nq) {
                float vv[4] = { stg[r].x, stg[r].y, stg[r].z, stg[r].w };
#pragma unroll
                for (int j = 0; j < 4; ++j) {
                    int f = 4 * fi + j;            // float index in chunk
                    glds[f % 3][ss][f / 3] = vv[j];
                }
            }
        }
        // issue next chunk's global loads early (latency hides under compute)
        if (c + 1 < c1) {
            int qb2 = (c + 1) * CHUNK_Q;
            int nq2 = QUADS - qb2; if (nq2 > CHUNK_Q) nq2 = CHUNK_Q;
#pragma unroll
            for (int r = 0; r < 3; ++r) {
                int fi = si + r * 128;
                if (fi < 3 * nq2) stg[r] = gsrc[(size_t)qb2 * 3 + fi];
            }
        }
        __syncthreads();   // chunk staged
#pragma unroll
        for (int sub = 0; sub < 2; ++sub) {
            int qq = lane + sub * 64;
            if (qq < nq) {
                const float4* p4 = (const float4*)(pb + 12 * (size_t)(qb + qq));
                float4 Pa = p4[0], Pc = p4[1], Pd = p4[2];
                float x[4] = { Pa.x, Pa.w, Pc.z, Pd.y };
                float y[4] = { Pa.y, Pc.x, Pc.w, Pd.z };
                float z[4] = { Pa.z, Pc.y, Pd.x, Pd.w };
#pragma unroll
                for (int gg = 0; gg < 4; ++gg) {
                    float4 GX = *(const float4*)&glds[0][gg][4 * qq];
                    float4 GY = *(const float4*)&glds[1][gg][4 * qq];
                    float4 GZ = *(const float4*)&glds[2][gg][4 * qq];
                    float gxv[4] = { GX.x, GX.y, GX.z, GX.w };
                    float gyv[4] = { GY.x, GY.y, GY.z, GY.w };
                    float gzv[4] = { GZ.x, GZ.y, GZ.z, GZ.w };
#pragma unroll
                    for (int k = 0; k < 4; ++k) {
                        v2f gxy = v2(gxv[k], gyv[k]);
                        a01[gg] = vfma(vsplat(x[k]), gxy, a01[gg]);
                        a34[gg] = vfma(vsplat(y[k]), gxy, a34[gg]);
                        a67[gg] = vfma(vsplat(z[k]), gxy, a67[gg]);
                        a25[gg] = vfma(v2(x[k], y[k]), vsplat(gzv[k]), a25[gg]);
                        a8[gg]  = fmaf(z[k], gzv[k], a8[gg]);
                    }
                }
            }
        }
    }

    // per-wave butterfly; (qhalf, pair) owned by exactly this wave
    float K[4][9];
#pragma unroll
    for (int i = 0; i < 4; ++i) {
        K[i][0] = a01[i].x; K[i][1] = a01[i].y; K[i][2] = a25[i].x;
        K[i][3] = a34[i].x; K[i][4] = a34[i].y; K[i][5] = a25[i].y;
        K[i][6] = a67[i].x; K[i][7] = a67[i].y; K[i][8] = a8[i];
    }
#pragma unroll
    for (int i = 0; i < 4; ++i)
#pragma unroll
        for (int j = 0; j < 9; ++j) {
            float v = K[i][j];
            v += __shfl_xor(v, 1);  v += __shfl_xor(v, 2);
            v += __shfl_xor(v, 4);  v += __shfl_xor(v, 8);
            v += __shfl_xor(v, 16); v += __shfl_xor(v, 32);
            K[i][j] = v;
        }
    if (lane == 0) {
#pragma unroll
        for (int gg = 0; gg < 4; ++gg)
#pragma unroll
            for (int j = 0; j < 9; ++j)
                ws->Kmat[qhalf][(gbase + gg) * P_ + p][j] = K[gg][j];
    }
}

// ---------------- kernel 2: per-pair SVD -> A = scale*R, t ----------------
__global__ void pair_svd(WS* __restrict__ ws) {
    int pair = blockIdx.x * blockDim.x + threadIdx.x;
    if (pair >= NPAIR) return;
    int p = pair & 31;
    int g = pair >> 5;

    double mp[3] = { ws->mu_p[p][0], ws->mu_p[p][1], ws->mu_p[p][2] };
    double mg[3] = { ws->mu_g[g][0], ws->mu_g[g][1], ws->mu_g[g][2] };
    double varp = (double)ws->var_p[p];

    double K[3][3];
#pragma unroll
    for (int a = 0; a < 3; ++a)
#pragma unroll
        for (int b = 0; b < 3; ++b)
            K[a][b] = (double)ws->Kmat[0][pair][3 * a + b] +
                      (double)ws->Kmat[1][pair][3 * a + b] -
                      (double)M_ * mp[a] * mg[b];

    // S = K^T K (symmetric PSD)
    double S[3][3];
#pragma unroll
    for (int a = 0; a < 3; ++a)
#pragma unroll
        for (int b = 0; b < 3; ++b) {
            double acc = 0.0;
#pragma unroll
            for (int c = 0; c < 3; ++c) acc += K[c][a] * K[c][b];
            S[a][b] = acc;
        }

    // Jacobi eigendecomposition S = V Lambda V^T
    double V[3][3] = { {1, 0, 0}, {0, 1, 0}, {0, 0, 1} };
    double tr = S[0][0] + S[1][1] + S[2][2];
    double tol = 1e-30 * tr * tr + 1e-300;
    const int PP[3] = {0, 0, 1};
    const int QQ[3] = {1, 2, 2};
    for (int sweep = 0; sweep < 30; ++sweep) {
        double off = S[0][1] * S[0][1] + S[0][2] * S[0][2] + S[1][2] * S[1][2];
        if (off <= tol) break;
        for (int r3 = 0; r3 < 3; ++r3) {
            int pq = PP[r3], qq = QQ[r3];
            double apq = S[pq][qq];
            if (apq == 0.0) continue;
            double theta = (S[qq][qq] - S[pq][pq]) / (2.0 * apq);
            double tt = copysign(1.0, theta) / (fabs(theta) + sqrt(theta * theta + 1.0));
            double c = 1.0 / sqrt(tt * tt + 1.0);
            double sj = tt * c;
            for (int r = 0; r < 3; ++r) {
                double srp = S[r][pq], srq = S[r][qq];
                S[r][pq] = c * srp - sj * srq;
                S[r][qq] = sj * srp + c * srq;
            }
            for (int cc = 0; cc < 3; ++cc) {
                double spr = S[pq][cc], sqr = S[qq][cc];
                S[pq][cc] = c * spr - sj * sqr;
                S[qq][cc] = sj * spr + c * sqr;
            }
            for (int r = 0; r < 3; ++r) {
                double vrp = V[r][pq], vrq = V[r][qq];
                V[r][pq] = c * vrp - sj * vrq;
                V[r][qq] = sj * vrp + c * vrq;
            }
        }
    }

    double lam[3] = { S[0][0], S[1][1], S[2][2] };
    int idx[3] = { 0, 1, 2 };
    if (lam[idx[0]] < lam[idx[1]]) { int tt = idx[0]; idx[0] = idx[1]; idx[1] = tt; }
    if (lam[idx[0]] < lam[idx[2]]) { int tt = idx[0]; idx[0] = idx[2]; idx[2] = tt; }
    if (lam[idx[1]] < lam[idx[2]]) { int tt = idx[1]; idx[1] = idx[2]; idx[2] = tt; }
    double Vs[3][3];
    double sv[3];
#pragma unroll
    for (int i = 0; i < 3; ++i) {
        double l = lam[idx[i]];
        sv[i] = sqrt(l > 0.0 ? l : 0.0);
        for (int r = 0; r < 3; ++r) Vs[r][i] = V[r][idx[i]];
    }

    double U[3][3];
#pragma unroll
    for (int i = 0; i < 3; ++i) {
        double kx = K[0][0] * Vs[0][i] + K[0][1] * Vs[1][i] + K[0][2] * Vs[2][i];
        double ky = K[1][0] * Vs[0][i] + K[1][1] * Vs[1][i] + K[1][2] * Vs[2][i];
        double kz = K[2][0] * Vs[0][i] + K[2][1] * Vs[1][i] + K[2][2] * Vs[2][i];
        double inv = (sv[i] > 1e-12 * sv[0] && sv[i] > 0.0) ? 1.0 / sv[i] : 0.0;
        U[0][i] = kx * inv; U[1][i] = ky * inv; U[2][i] = kz * inv;
    }
    if (sv[2] <= 1e-12 * sv[0] || sv[0] == 0.0) {
        U[0][2] = U[1][0] * U[2][1] - U[2][0] * U[1][1];
        U[1][2] = U[2][0] * U[0][1] - U[0][0] * U[2][1];
        U[2][2] = U[0][0] * U[1][1] - U[1][0] * U[0][1];
    }

    double detK = K[0][0] * (K[1][1] * K[2][2] - K[1][2] * K[2][1])
                - K[0][1] * (K[1][0] * K[2][2] - K[1][2] * K[2][0])
                + K[0][2] * (K[1][0] * K[2][1] - K[1][1] * K[2][0]);
    double d = (detK >= 0.0) ? 1.0 : -1.0;
    double scale = (sv[0] + sv[1] + d * sv[2]) / varp;

    float A[9];
#pragma unroll
    for (int a = 0; a < 3; ++a)
#pragma unroll
        for (int b = 0; b < 3; ++b) {
            double r = Vs[a][0] * U[b][0] + Vs[a][1] * U[b][1] + d * Vs[a][2] * U[b][2];
            A[3 * a + b] = (float)(scale * r);
        }
    float tvec[3];
#pragma unroll
    for (int a = 0; a < 3; ++a)
        tvec[a] = (float)(mg[a] - ((double)A[3 * a + 0] * mp[0] + (double)A[3 * a + 1] * mp[1] +
                                   (double)A[3 * a + 2] * mp[2]));

#pragma unroll
    for (int j = 0; j < 9; ++j) ws->At[pair][j] = A[j];
#pragma unroll
    for (int j = 0; j < 3; ++j) ws->At[pair][9 + j] = tvec[j];
}

// ---------------- kernel 3: packed v2v error (2p x 4g, AoS) ----------------
// Proven R0 shape: 1024 blocks, VGPR 48 / SGPR 112, VALUBusy ~65%, ~72 us.
__global__ __launch_bounds__(256, 3) void pair_error_p(const float* __restrict__ pred,
                                                       const float* __restrict__ gt,
                                                       WS* __restrict__ ws) {
    int bx = blockIdx.x;
    int gbase = (bx & 63) * 4;
    int pbase = (bx >> 6) * 2;
    int t = threadIdx.x;

    v2f a03[8], a14[8], a25v[8], t01[8];
    float a6[8], a7[8], a8v[8], t2[8];
#pragma unroll
    for (int gg = 0; gg < 4; ++gg)
#pragma unroll
        for (int pp = 0; pp < 2; ++pp) {
            int i = gg * 2 + pp;
            const float* At = ws->At[(gbase + gg) * P_ + (pbase + pp)];
            a03[i] = v2(At[0], At[3]);
            a14[i] = v2(At[1], At[4]);
            a25v[i] = v2(At[2], At[5]);
            t01[i] = v2(At[9], At[10]);
            a6[i] = At[6]; a7[i] = At[7]; a8v[i] = At[8]; t2[i] = At[11];
        }

    const float* pb0 = pred + (size_t)pbase * (M_ * 3);
    const float* pb1 = pred + (size_t)(pbase + 1) * (M_ * 3);
    const float* gb[4];
#pragma unroll
    for (int j = 0; j < 4; ++j) gb[j] = gt + (size_t)(gbase + j) * (M_ * 3);

    float acc[8];
#pragma unroll
    for (int i = 0; i < 8; ++i) acc[i] = 0.f;

    for (int q = t; q < QUADS; q += 256) {
        float4 P[2][3];
        {
            const float4* p4 = (const float4*)(pb0 + 12 * (size_t)q);
            P[0][0] = p4[0]; P[0][1] = p4[1]; P[0][2] = p4[2];
            p4 = (const float4*)(pb1 + 12 * (size_t)q);
            P[1][0] = p4[0]; P[1][1] = p4[1]; P[1][2] = p4[2];
        }
#pragma unroll
        for (int gg = 0; gg < 4; ++gg) {
            const float4* g4 = (const float4*)(gb[gg] + 12 * (size_t)q);
            float4 Ga = g4[0], Gc = g4[1], Gd = g4[2];
            v2f gxy[4] = { v2(Ga.x, Ga.y), v2(Ga.w, Gc.x), v2(Gc.z, Gc.w), v2(Gd.y, Gd.z) };
            float gz[4] = { Ga.z, Gc.y, Gd.x, Gd.w };
#pragma unroll
            for (int pp = 0; pp < 2; ++pp) {
                int i = gg * 2 + pp;
                float4 Pa = P[pp][0], Pc = P[pp][1], Pd = P[pp][2];
                float x[4] = { Pa.x, Pa.w, Pc.z, Pd.y };
                float y[4] = { Pa.y, Pc.x, Pc.w, Pd.z };
                float z[4] = { Pa.z, Pc.y, Pd.x, Pd.w };
                float s = 0.f;
#pragma unroll
                for (int k = 0; k < 4; ++k) {
                    v2f dd = vfma(a03[i], vsplat(x[k]),
                             vfma(a14[i], vsplat(y[k]),
                             vfma(a25v[i], vsplat(z[k]), t01[i])));
                    dd = dd - gxy[k];
                    float dz = fmaf(a6[i], x[k], fmaf(a7[i], y[k], fmaf(a8v[i], z[k], t2[i]))) - gz[k];
                    v2f m = dd * dd;
                    s += __builtin_amdgcn_sqrtf(fmaf(dz, dz, m.x + m.y));
                }
                acc[i] += s;
            }
        }
    }

#pragma unroll
    for (int i = 0; i < 8; ++i) {
        float v = acc[i];
        v += __shfl_xor(v, 1);  v += __shfl_xor(v, 2);
        v += __shfl_xor(v, 4);  v += __shfl_xor(v, 8);
        v += __shfl_xor(v, 16); v += __shfl_xor(v, 32);
        acc[i] = v;
    }
    __shared__ float part[4][8];
    int lane = t & 63, wave = t >> 6;
    if (lane == 0) {
#pragma unroll
        for (int i = 0; i < 8; ++i) part[wave][i] = acc[i];
    }
    __syncthreads();
    if (t < 8) {
        float s = part[0][t] + part[1][t] + part[2][t] + part[3][t];
        int gg = t >> 1, pp = t & 1;
        ws->pair_err[(gbase + gg) * P_ + (pbase + pp)] = s / (float)M_;
    }
}

// ---------------- kernel 4: argmin over gallery + write outputs ----------------
__global__ void argmin_out(const WS* __restrict__ ws, float* __restrict__ out) {
    __shared__ float be[8][32];
    __shared__ int   bg[8][32];
    int t = threadIdx.x;
    int p = t & 31, slice = t >> 5;
    float best = 3.4e38f;
    int bi = G_;
    for (int g = slice; g < G_; g += 8) {
        float e = ws->pair_err[g * P_ + p];
        if (e < best) { best = e; bi = g; }
    }
    be[slice][p] = best;
    bg[slice][p] = bi;
    __syncthreads();
    if (t < P_) {
        float b0 = be[0][t];
        int   i0 = bg[0][t];
        for (int s = 1; s < 8; ++s) {
            float e = be[s][t];
            int   i = bg[s][t];
            if (e < b0 || (e == b0 && i < i0)) { b0 = e; i0 = i; }
        }
        out[t] = (float)i0;
        out[P_ + t] = b0;
    }
}

extern "C" void kernel_launch(void* const* d_in, const int* in_sizes, int n_in,
                              void* d_out, int out_size, void* d_ws, size_t ws_size,
                              hipStream_t stream) {
    const float* pred = (const float*)d_in[0];   // (32, 2, 6890, 3)
    const float* gt   = (const float*)d_in[1];   // (256, 2, 6890, 3)
    float* out = (float*)d_out;                  // 64 floats: mapping(32) | min_error(32)
    WS* ws = (WS*)d_ws;                          // ~1 MB used

    crosscov_ws<<<dim3(NB_WS + P_ + G_), dim3(512), 0, stream>>>(pred, gt, ws);
    pair_svd<<<dim3(NPAIR / 64), dim3(64), 0, stream>>>(ws);
    pair_error_p<<<dim3(16 * 64), dim3(256), 0, stream>>>(pred, gt, ws);
    argmin_out<<<dim3(1), dim3(256), 0, stream>>>(ws, out);
}